// Round 3
// baseline (30058.588 us; speedup 1.0000x reference)
//
#include <hip/hip_runtime.h>
#include <hip/hip_bf16.h>

#define B_ 16
#define N_ 2048

// ---------------- elementwise utilities ----------------

static __global__ void zerof_kernel(float* p, long long n) {
  long long i = (long long)blockIdx.x * blockDim.x + threadIdx.x;
  long long st = (long long)gridDim.x * blockDim.x;
  for (; i < n; i += st) p[i] = 0.f;
}

// sq[row] = sum_f X[row,f]^2   (rows = G*N)
static __global__ void rowsq_kernel(const float* __restrict__ X, float* __restrict__ sq, int F) {
  int row = blockIdx.x;
  const float* xr = X + (long long)row * F;
  float s = 0.f;
  for (int f = threadIdx.x; f < F; f += blockDim.x) { float v = xr[f]; s += v * v; }
  __shared__ float red[256];
  red[threadIdx.x] = s;
  __syncthreads();
  for (int st = 128; st > 0; st >>= 1) {
    if (threadIdx.x < st) red[threadIdx.x] += red[threadIdx.x + st];
    __syncthreads();
  }
  if (threadIdx.x == 0) sq[row] = red[0];
}

// A[b,i,j] = exp(-(sq_i + sq_j - 2 x_i.x_j)), diagonal forced to 0
static __global__ __launch_bounds__(256) void graph_kernel(
    const float* __restrict__ X, const float* __restrict__ sq,
    float* A, int N, int F) {
  int b = blockIdx.z;
  const float* Xb = X + (long long)b * N * F;
  const float* sqb = sq + (long long)b * N;
  float* Ab = A + (long long)b * N * N;
  __shared__ __align__(16) float Xi[16][68];
  __shared__ __align__(16) float Xj[16][68];
  int i0 = blockIdx.y * 64, j0 = blockIdx.x * 64;
  int tx = threadIdx.x & 15, ty = threadIdx.x >> 4;
  float acc[4][4] = {};
  for (int f0 = 0; f0 < F; f0 += 16) {
    for (int t = threadIdx.x; t < 1024; t += 256) {
      int r = t >> 4, c = t & 15;
      float vi = 0.f, vj = 0.f;
      if (f0 + c < F) {
        vi = Xb[(long long)(i0 + r) * F + f0 + c];
        vj = Xb[(long long)(j0 + r) * F + f0 + c];
      }
      Xi[c][r] = vi;
      Xj[c][r] = vj;
    }
    __syncthreads();
#pragma unroll
    for (int kk = 0; kk < 16; ++kk) {
      float4 a4 = *reinterpret_cast<const float4*>(&Xi[kk][ty * 4]);
      float4 b4 = *reinterpret_cast<const float4*>(&Xj[kk][tx * 4]);
      float a[4] = {a4.x, a4.y, a4.z, a4.w};
      float bv[4] = {b4.x, b4.y, b4.z, b4.w};
#pragma unroll
      for (int i = 0; i < 4; ++i)
#pragma unroll
        for (int j = 0; j < 4; ++j) acc[i][j] += a[i] * bv[j];
    }
    __syncthreads();
  }
  for (int i = 0; i < 4; ++i) {
    int gi = i0 + ty * 4 + i;
    float si = sqb[gi];
    for (int j = 0; j < 4; ++j) {
      int gj = j0 + tx * 4 + j;
      float d2 = si + sqb[gj] - 2.f * acc[i][j];
      float v = (gi == gj) ? 0.f : expf(-d2);
      Ab[(long long)gi * N + gj] = v;
    }
  }
}

// dinv[row] = deg>0 ? rsqrt(deg) : 0
static __global__ void rowsum_dinv_kernel(const float* __restrict__ A, float* __restrict__ dinv, int N) {
  long long row = blockIdx.x;
  const float* ar = A + row * N;
  float s = 0.f;
  for (int j = threadIdx.x; j < N; j += blockDim.x) s += ar[j];
  __shared__ float red[256];
  red[threadIdx.x] = s;
  __syncthreads();
  for (int st = 128; st > 0; st >>= 1) {
    if (threadIdx.x < st) red[threadIdx.x] += red[threadIdx.x + st];
    __syncthreads();
  }
  if (threadIdx.x == 0) {
    float d = red[0];
    dinv[row] = (d > 0.f) ? rsqrtf(d) : 0.f;
  }
}

// Lhat = -dinv_i * A_ij * dinv_j   (in place), rows chunk-global
static __global__ void scaleL_kernel(float* A, const float* __restrict__ dinv, int N, long long total) {
  long long i = (long long)blockIdx.x * blockDim.x + threadIdx.x;
  long long st = (long long)gridDim.x * blockDim.x;
  for (; i < total; i += st) {
    long long bn = i / N;
    int j = (int)(i - bn * N);
    long long b = bn / N;
    int r = (int)(bn - b * N);
    A[i] = -A[i] * dinv[b * N + r] * dinv[b * N + j];
  }
}

// H = relu(H + bias[f])
static __global__ void bias_relu_kernel(float* H, const float* __restrict__ bias, long long total, int F) {
  long long i = (long long)blockIdx.x * blockDim.x + threadIdx.x;
  long long st = (long long)gridDim.x * blockDim.x;
  for (; i < total; i += st) {
    int f = (int)(i % F);
    H[i] = fmaxf(H[i] + bias[f], 0.f);
  }
}

// ---------------- generic batched f32 GEMM ----------------
// C[b] = alpha * A[b](MxK) @ Bm[b](KxNc) + beta * D[b](MxNc); D may be null or alias C.
static __global__ __launch_bounds__(256) void gemm_f32(
    const float* __restrict__ A, const float* __restrict__ Bm,
    const float* D, float* C,
    int M, int K, int Nc,
    long long sA, long long sB, long long sD, long long sC,
    float alpha, float beta) {
  int b = blockIdx.z;
  A += (long long)b * sA;
  Bm += (long long)b * sB;
  C += (long long)b * sC;
  if (D) D += (long long)b * sD;
  __shared__ __align__(16) float As[16][68];
  __shared__ __align__(16) float Bs[16][68];
  int row0 = blockIdx.y * 64, col0 = blockIdx.x * 64;
  int tx = threadIdx.x & 15, ty = threadIdx.x >> 4;
  float acc[4][4] = {};
  for (int k0 = 0; k0 < K; k0 += 16) {
    for (int t = threadIdx.x; t < 1024; t += 256) {
      int r = t >> 4, c = t & 15;
      float v = 0.f;
      if (row0 + r < M && k0 + c < K) v = A[(long long)(row0 + r) * K + k0 + c];
      As[c][r] = v;
    }
    for (int t = threadIdx.x; t < 1024; t += 256) {
      int r = t >> 6, c = t & 63;
      float v = 0.f;
      if (k0 + r < K && col0 + c < Nc) v = Bm[(long long)(k0 + r) * Nc + col0 + c];
      Bs[r][c] = v;
    }
    __syncthreads();
#pragma unroll
    for (int kk = 0; kk < 16; ++kk) {
      float4 a4 = *reinterpret_cast<const float4*>(&As[kk][ty * 4]);
      float4 b4 = *reinterpret_cast<const float4*>(&Bs[kk][tx * 4]);
      float a[4] = {a4.x, a4.y, a4.z, a4.w};
      float bv[4] = {b4.x, b4.y, b4.z, b4.w};
#pragma unroll
      for (int i = 0; i < 4; ++i)
#pragma unroll
        for (int j = 0; j < 4; ++j) acc[i][j] += a[i] * bv[j];
    }
    __syncthreads();
  }
  for (int i = 0; i < 4; ++i) {
    int r = row0 + ty * 4 + i;
    if (r >= M) continue;
    for (int j = 0; j < 4; ++j) {
      int c = col0 + tx * 4 + j;
      if (c >= Nc) continue;
      long long idx = (long long)r * Nc + c;
      float v = alpha * acc[i][j];
      if (D) v += beta * D[idx];
      C[idx] = v;
    }
  }
}

// M[f,g] += sum_b sum_n H[b,n,f] * LH[b,n,g]
static __global__ __launch_bounds__(256) void atb_kernel(
    const float* __restrict__ H, const float* __restrict__ LH,
    float* Mout, int N, int F) {
  int b = blockIdx.z;
  const float* Hb = H + (long long)b * N * F;
  const float* Lb = LH + (long long)b * N * F;
  __shared__ __align__(16) float Hs[16][68];
  __shared__ __align__(16) float Ls[16][68];
  int f0 = blockIdx.y * 64, g0 = blockIdx.x * 64;
  int tx = threadIdx.x & 15, ty = threadIdx.x >> 4;
  float acc[4][4] = {};
  for (int n0 = 0; n0 < N; n0 += 16) {
    for (int t = threadIdx.x; t < 1024; t += 256) {
      int k = t >> 6, c = t & 63;
      Hs[k][c] = Hb[(long long)(n0 + k) * F + f0 + c];
      Ls[k][c] = Lb[(long long)(n0 + k) * F + g0 + c];
    }
    __syncthreads();
#pragma unroll
    for (int kk = 0; kk < 16; ++kk) {
      float4 a4 = *reinterpret_cast<const float4*>(&Hs[kk][ty * 4]);
      float4 b4 = *reinterpret_cast<const float4*>(&Ls[kk][tx * 4]);
      float a[4] = {a4.x, a4.y, a4.z, a4.w};
      float bv[4] = {b4.x, b4.y, b4.z, b4.w};
#pragma unroll
      for (int i = 0; i < 4; ++i)
#pragma unroll
        for (int j = 0; j < 4; ++j) acc[i][j] += a[i] * bv[j];
    }
    __syncthreads();
  }
  for (int i = 0; i < 4; ++i)
    for (int j = 0; j < 4; ++j)
      atomicAdd(&Mout[(long long)(f0 + ty * 4 + i) * F + g0 + tx * 4 + j], acc[i][j]);
}

// out += sum(src^2)
static __global__ void sumsq_kernel(const float* __restrict__ src, long long n, float* out) {
  float s = 0.f;
  long long i = (long long)blockIdx.x * blockDim.x + threadIdx.x;
  long long st = (long long)gridDim.x * blockDim.x;
  for (; i < n; i += st) { float v = src[i]; s += v * v; }
  __shared__ float red[256];
  red[threadIdx.x] = s;
  __syncthreads();
  for (int stp = 128; stp > 0; stp >>= 1) {
    if (threadIdx.x < stp) red[threadIdx.x] += red[threadIdx.x + stp];
    __syncthreads();
  }
  if (threadIdx.x == 0) atomicAdd(out, red[0]);
}

// g[idx] = max_n H[b,n,f]  (b chunk-local)
static __global__ void maxpool_kernel(const float* __restrict__ H, float* g, int N, int F, int total) {
  int idx = blockIdx.x * blockDim.x + threadIdx.x;
  if (idx >= total) return;
  int b = idx / F, f = idx - b * F;
  const float* hb = H + (long long)b * N * F + f;
  float m = -INFINITY;
  for (int n = 0; n < N; ++n) m = fmaxf(m, hb[(long long)n * F]);
  g[idx] = m;
}

// out[b,j] = (relu?) sum_k in[b,k] * W[j,k] + bias[j]
static __global__ void fc_kernel(const float* __restrict__ in, const float* __restrict__ W,
                                 const float* __restrict__ bias, float* out,
                                 int Bc, int K, int J, int do_relu) {
  int gtid = blockIdx.x * blockDim.x + threadIdx.x;
  int wid = gtid >> 6;
  int lane = gtid & 63;
  if (wid >= Bc * J) return;
  int b = wid / J, j = wid - b * J;
  const float* ib = in + (long long)b * K;
  const float* wj = W + (long long)j * K;
  float s = 0.f;
  for (int k = lane; k < K; k += 64) s += ib[k] * wj[k];
  for (int off = 32; off > 0; off >>= 1) s += __shfl_down(s, off);
  if (lane == 0) {
    s += bias[j];
    out[wid] = do_relu ? fmaxf(s, 0.f) : s;
  }
}

// regs: [reg1, reg2, reg3, nw, nb, nw, nb, nw, nb]
static __global__ void finalize_kernel(const float* scal, float* out_regs) {
  if (threadIdx.x == 0 && blockIdx.x == 0) {
    float r1 = sqrtf(scal[0]), r2 = sqrtf(scal[1]), r3 = sqrtf(scal[2]);
    float nw = sqrtf(scal[3]), nb = sqrtf(scal[4]);
    out_regs[0] = r1; out_regs[1] = r2; out_regs[2] = r3;
    out_regs[3] = nw; out_regs[4] = nb;
    out_regs[5] = nw; out_regs[6] = nb;
    out_regs[7] = nw; out_regs[8] = nb;
  }
}

// ---------------- host orchestration ----------------

extern "C" void kernel_launch(void* const* d_in, const int* in_sizes, int n_in,
                              void* d_out, int out_size, void* d_ws, size_t ws_size,
                              hipStream_t stream) {
  const float* x   = (const float*)d_in[0];
  const float* w1  = (const float*)d_in[4];
  const float* b1  = (const float*)d_in[5];
  const float* w2  = (const float*)d_in[6];
  const float* b2  = (const float*)d_in[7];
  const float* w3  = (const float*)d_in[8];
  const float* b3  = (const float*)d_in[9];
  const float* fw1 = (const float*)d_in[10];
  const float* fb1 = (const float*)d_in[11];
  const float* fw2 = (const float*)d_in[12];
  const float* fb2 = (const float*)d_in[13];
  const float* fw3 = (const float*)d_in[14];
  const float* fb3 = (const float*)d_in[15];
  float* out = (float*)d_out;

  const long long NN = (long long)N_ * N_;

  // adaptive chunk size: largest G in {4,2,1} whose footprint fits ws_size
  auto footprint = [&](int G) -> unsigned long long {
    unsigned long long f = 0;
    f += (unsigned long long)G * NN;          // L
    f += (unsigned long long)G * N_ * 1024;   // TxA+TxB (= LH alias region)
    f += (unsigned long long)G * N_ * 128;    // H1c
    f += (unsigned long long)G * N_ * 512;    // H2c
    f += (unsigned long long)G * N_ * 1024;   // H3c
    f += 128ULL * 128 + 512ULL * 512 + 1024ULL * 1024;  // Mm1..3
    f += (unsigned long long)G * N_ * 2;      // sq, dinv
    f += (unsigned long long)B_ * (1024 + 512 + 128) + 64;
    return f * 4ULL;
  };
  int G = 4;
  while (G > 1 && footprint(G) > ws_size) G >>= 1;
  if (footprint(G) > ws_size) return;  // diagnostic: clean failure instead of OOB crash

  // workspace layout (floats)
  float* ws = (float*)d_ws;
  long long off = 0;
  float* L4  = ws + off; off += (long long)G * NN;
  float* TxA = ws + off; off += (long long)G * N_ * 512;
  float* TxB = ws + off; off += (long long)G * N_ * 512;
  float* H1c = ws + off; off += (long long)G * N_ * 128;
  float* H2c = ws + off; off += (long long)G * N_ * 512;
  float* H3c = ws + off; off += (long long)G * N_ * 1024;
  float* Mm1 = ws + off; off += 128 * 128;
  float* Mm2 = ws + off; off += 512 * 512;
  float* Mm3 = ws + off; off += 1024 * 1024;
  float* sq  = ws + off; off += (long long)G * N_;
  float* dinv= ws + off; off += (long long)G * N_;
  float* gb  = ws + off; off += (long long)B_ * 1024;
  float* o1  = ws + off; off += (long long)B_ * 512;
  float* o2  = ws + off; off += (long long)B_ * 128;
  float* scal= ws + off; off += 16;
  float* LHc = TxA;  // aliases TxA+TxB: G*N_*1024 floats exactly

  auto gemm = [&](const float* A, const float* Bm, const float* D, float* C,
                  int M, int K, int Nc, int nb,
                  long long sA, long long sB, long long sD, long long sC,
                  float alpha, float beta) {
    dim3 grid((Nc + 63) / 64, (M + 63) / 64, nb);
    gemm_f32<<<grid, 256, 0, stream>>>(A, Bm, D, C, M, K, Nc, sA, sB, sD, sC, alpha, beta);
  };

  zerof_kernel<<<1, 256, 0, stream>>>(scal, 16);
  zerof_kernel<<<64, 256, 0, stream>>>(Mm1, 128LL * 128);
  zerof_kernel<<<256, 256, 0, stream>>>(Mm2, 512LL * 512);
  zerof_kernel<<<1024, 256, 0, stream>>>(Mm3, 1024LL * 1024);

  auto chunk_layer = [&](const float* Xc, int Fin, const float* Wk, const float* bias,
                         int K, int Fout, float* Hc, float* Mm) {
    const long long NFi = (long long)N_ * Fin;
    const long long NFo = (long long)N_ * Fout;
    // graph -> Lhat (G batches)
    rowsq_kernel<<<G * N_, 256, 0, stream>>>(Xc, sq, Fin);
    graph_kernel<<<dim3(N_ / 64, N_ / 64, G), 256, 0, stream>>>(Xc, sq, L4, N_, Fin);
    rowsum_dinv_kernel<<<G * N_, 256, 0, stream>>>(L4, dinv, N_);
    scaleL_kernel<<<4096, 256, 0, stream>>>(L4, dinv, N_, (long long)G * NN);
    // chebyshev: Hc = sum_k T_k @ W[k]
    gemm(Xc, Wk, nullptr, Hc, G * N_, Fin, Fout, 1, 0, 0, 0, 0, 1.f, 0.f);
    if (K > 1) {
      gemm(L4, Xc, nullptr, TxA, N_, N_, Fin, G, NN, NFi, 0, NFi, 1.f, 0.f);  // T1
      gemm(TxA, Wk + (long long)Fin * Fout, Hc, Hc, G * N_, Fin, Fout, 1, 0, 0, 0, 0, 1.f, 1.f);
      const float* prev2 = Xc;
      float* prev1 = TxA;
      for (int k = 2; k < K; ++k) {
        float* dst = (k == 2) ? TxB : (float*)prev2;
        gemm(L4, prev1, prev2, dst, N_, N_, Fin, G, NN, NFi, NFi, NFi, 2.f, -1.f);
        gemm(dst, Wk + (long long)k * Fin * Fout, Hc, Hc, G * N_, Fin, Fout, 1, 0, 0, 0, 0, 1.f, 1.f);
        prev2 = prev1; prev1 = dst;
      }
    }
    bias_relu_kernel<<<4096, 256, 0, stream>>>(Hc, bias, (long long)G * NFo, Fout);
    // regularizer: LHc = (I + Lhat) h ; Mm += h^T LHc  (Tx buffers dead now)
    gemm(L4, Hc, Hc, LHc, N_, N_, Fout, G, NN, NFo, NFo, NFo, 1.f, 1.f);
    atb_kernel<<<dim3(Fout / 64, Fout / 64, G), 256, 0, stream>>>(Hc, LHc, Mm, N_, Fout);
  };

  for (int c = 0; c < B_ / G; ++c) {
    const float* Xc = x + (long long)c * G * N_ * 6;
    chunk_layer(Xc,  6,   w1, b1, 6, 128,  H1c, Mm1);
    chunk_layer(H1c, 128, w2, b2, 5, 512,  H2c, Mm2);
    chunk_layer(H2c, 512, w3, b3, 3, 1024, H3c, Mm3);
    maxpool_kernel<<<(G * 1024 + 255) / 256, 256, 0, stream>>>(
        H3c, gb + (long long)c * G * 1024, N_, 1024, G * 1024);
  }

  sumsq_kernel<<<64, 256, 0, stream>>>(Mm1, 128LL * 128, scal + 0);
  sumsq_kernel<<<256, 256, 0, stream>>>(Mm2, 512LL * 512, scal + 1);
  sumsq_kernel<<<256, 256, 0, stream>>>(Mm3, 1024LL * 1024, scal + 2);

  // global max pool done per chunk; FC head
  fc_kernel<<<(B_ * 512 * 64 + 255) / 256, 256, 0, stream>>>(gb, fw1, fb1, o1, B_, 1024, 512, 1);
  fc_kernel<<<(B_ * 128 * 64 + 255) / 256, 256, 0, stream>>>(o1, fw2, fb2, o2, B_, 512, 128, 1);
  fc_kernel<<<(B_ * 10 * 64 + 255) / 256, 256, 0, stream>>>(o2, fw3, fb3, out, B_, 128, 10, 0);

  // param norms + finalize regs
  sumsq_kernel<<<256, 256, 0, stream>>>(fw1, 512LL * 1024, scal + 3);
  sumsq_kernel<<<1, 256, 0, stream>>>(fb1, 512LL, scal + 4);
  finalize_kernel<<<1, 64, 0, stream>>>(scal, out + 160);
}

// Round 4
// 18141.235 us; speedup vs baseline: 1.6569x; 1.6569x over previous
//
#include <hip/hip_runtime.h>

#define B_ 16
#define N_ 2048

typedef __attribute__((ext_vector_type(8))) short s16x8;
typedef __attribute__((ext_vector_type(4))) float f32x4;

__device__ inline unsigned short f2bf(float f) {
  unsigned u = __float_as_uint(f);
  u += 0x7FFFu + ((u >> 16) & 1u);
  return (unsigned short)(u >> 16);
}
__device__ inline float bf2f(unsigned short h) {
  return __uint_as_float(((unsigned)h) << 16);
}

// ---------------- elementwise utilities ----------------

static __global__ void zerof_kernel(float* p, long long n) {
  long long i = (long long)blockIdx.x * blockDim.x + threadIdx.x;
  long long st = (long long)gridDim.x * blockDim.x;
  for (; i < n; i += st) p[i] = 0.f;
}

static __global__ void rowsq_kernel(const float* __restrict__ X, float* __restrict__ sq, int F) {
  int row = blockIdx.x;
  const float* xr = X + (long long)row * F;
  float s = 0.f;
  for (int f = threadIdx.x; f < F; f += blockDim.x) { float v = xr[f]; s += v * v; }
  __shared__ float red[256];
  red[threadIdx.x] = s;
  __syncthreads();
  for (int st = 128; st > 0; st >>= 1) {
    if (threadIdx.x < st) red[threadIdx.x] += red[threadIdx.x + st];
    __syncthreads();
  }
  if (threadIdx.x == 0) sq[row] = red[0];
}

static __global__ void rowsum_dinv_kernel(const float* __restrict__ A, float* __restrict__ dinv, int N) {
  long long row = blockIdx.x;
  const float* ar = A + row * N;
  float s = 0.f;
  for (int j = threadIdx.x; j < N; j += blockDim.x) s += ar[j];
  __shared__ float red[256];
  red[threadIdx.x] = s;
  __syncthreads();
  for (int st = 128; st > 0; st >>= 1) {
    if (threadIdx.x < st) red[threadIdx.x] += red[threadIdx.x + st];
    __syncthreads();
  }
  if (threadIdx.x == 0) {
    float d = red[0];
    dinv[row] = (d > 0.f) ? rsqrtf(d) : 0.f;
  }
}

static __global__ void scaleL_kernel(float* A, const float* __restrict__ dinv, int N, long long total) {
  long long i = (long long)blockIdx.x * blockDim.x + threadIdx.x;
  long long st = (long long)gridDim.x * blockDim.x;
  for (; i < total; i += st) {
    long long bn = i / N;
    int j = (int)(i - bn * N);
    long long b = bn / N;
    int r = (int)(bn - b * N);
    A[i] = -A[i] * dinv[b * N + r] * dinv[b * N + j];
  }
}

static __global__ void bias_relu_kernel(float* H, const float* __restrict__ bias, long long total, int F) {
  long long i = (long long)blockIdx.x * blockDim.x + threadIdx.x;
  long long st = (long long)gridDim.x * blockDim.x;
  for (; i < total; i += st) {
    int f = (int)(i % F);
    H[i] = fmaxf(H[i] + bias[f], 0.f);
  }
}

// batched f32 transpose: dst[b][c][r] = src[b][r][c]; src is R x Cc row-major
static __global__ void transpose_f32(const float* __restrict__ src, float* __restrict__ dst,
                                     int R, int Cc, long long sS, long long sD) {
  int bz = blockIdx.z;
  src += (long long)bz * sS;
  dst += (long long)bz * sD;
  __shared__ float tile[32][33];
  int r0 = blockIdx.y * 32, c0 = blockIdx.x * 32;
  int tx = threadIdx.x, ty = threadIdx.y;  // block (32,8)
#pragma unroll
  for (int i = 0; i < 32; i += 8) {
    int r = r0 + ty + i, cx = c0 + tx;
    tile[ty + i][tx] = (r < R && cx < Cc) ? src[(long long)r * Cc + cx] : 0.f;
  }
  __syncthreads();
#pragma unroll
  for (int i = 0; i < 32; i += 8) {
    int cr = c0 + ty + i, rx = r0 + tx;
    if (cr < Cc && rx < R) dst[(long long)cr * R + rx] = tile[tx][ty + i];
  }
}

// ---------------- MFMA split-bf16 GEMM ----------------
// C[z] = alpha * A[z](MxK) * BT[z](NcxK)^T + beta * D[z]   (mode 0)
// mode 1 (graph): C[r][c] = (r==c) ? 0 : exp(-(sq[r]+sq[c]-2*acc))
// All matrices f32. Each operand split into bf16 hi+lo; 3 MFMAs per product.
static __global__ __launch_bounds__(256) void gemm_mf(
    const float* __restrict__ A, int lda, long long sA,
    const float* __restrict__ BT, int ldb, long long sB,
    const float* D, int ldd, long long sD,
    float* C, int ldc, long long sC,
    int M, int K, int Nc,
    float alpha, float beta,
    int mode, const float* sqp, long long sSq) {
  int bz = blockIdx.z;
  A += (long long)bz * sA;
  BT += (long long)bz * sB;
  C += (long long)bz * sC;
  if (D) D += (long long)bz * sD;
  const float* sqb = sqp ? sqp + (long long)bz * sSq : nullptr;

  __shared__ __align__(16) short aH[4096], aL[4096], bHs[4096], bLs[4096];

  int row0 = blockIdx.y * 128, col0 = blockIdx.x * 128;
  int t = threadIdx.x;
  int w = t >> 6, l = t & 63, g = l >> 4, c = l & 15;
  int wr = w >> 1, wc = w & 1;

  f32x4 acc[4][4];
#pragma unroll
  for (int i = 0; i < 4; ++i)
#pragma unroll
    for (int j = 0; j < 4; ++j) {
      acc[i][j][0] = 0.f; acc[i][j][1] = 0.f; acc[i][j][2] = 0.f; acc[i][j][3] = 0.f;
    }

  int sm = t >> 1;          // 0..127: tile row (A) / tile col (BT)
  int ks = (t & 1) << 4;    // 0 or 16
  int arow = row0 + sm;
  int brow = col0 + sm;
  bool a_vec = ((lda & 3) == 0);
  bool b_vec = ((ldb & 3) == 0);

  for (int k0 = 0; k0 < K; k0 += 32) {
    float va[16], vb[16];
    // ---- load A strip ----
    if (arow < M) {
      const float* src = A + (long long)arow * lda + k0 + ks;
      if (a_vec && (k0 + ks + 16 <= K)) {
        float4 p0 = *reinterpret_cast<const float4*>(src);
        float4 p1 = *reinterpret_cast<const float4*>(src + 4);
        float4 p2 = *reinterpret_cast<const float4*>(src + 8);
        float4 p3 = *reinterpret_cast<const float4*>(src + 12);
        va[0]=p0.x; va[1]=p0.y; va[2]=p0.z; va[3]=p0.w;
        va[4]=p1.x; va[5]=p1.y; va[6]=p1.z; va[7]=p1.w;
        va[8]=p2.x; va[9]=p2.y; va[10]=p2.z; va[11]=p2.w;
        va[12]=p3.x; va[13]=p3.y; va[14]=p3.z; va[15]=p3.w;
      } else {
#pragma unroll
        for (int j = 0; j < 16; ++j) va[j] = (k0 + ks + j < K) ? src[j] : 0.f;
      }
    } else {
#pragma unroll
      for (int j = 0; j < 16; ++j) va[j] = 0.f;
    }
    // ---- load BT strip ----
    if (brow < Nc) {
      const float* src = BT + (long long)brow * ldb + k0 + ks;
      if (b_vec && (k0 + ks + 16 <= K)) {
        float4 p0 = *reinterpret_cast<const float4*>(src);
        float4 p1 = *reinterpret_cast<const float4*>(src + 4);
        float4 p2 = *reinterpret_cast<const float4*>(src + 8);
        float4 p3 = *reinterpret_cast<const float4*>(src + 12);
        vb[0]=p0.x; vb[1]=p0.y; vb[2]=p0.z; vb[3]=p0.w;
        vb[4]=p1.x; vb[5]=p1.y; vb[6]=p1.z; vb[7]=p1.w;
        vb[8]=p2.x; vb[9]=p2.y; vb[10]=p2.z; vb[11]=p2.w;
        vb[12]=p3.x; vb[13]=p3.y; vb[14]=p3.z; vb[15]=p3.w;
      } else {
#pragma unroll
        for (int j = 0; j < 16; ++j) vb[j] = (k0 + ks + j < K) ? src[j] : 0.f;
      }
    } else {
#pragma unroll
      for (int j = 0; j < 16; ++j) vb[j] = 0.f;
    }
    // ---- convert to hi/lo bf16 and store to LDS (blocked [kg][128][8]) ----
    s16x8 ah0, ah1, al0, al1, bh0, bh1, bl0, bl1;
#pragma unroll
    for (int j = 0; j < 8; ++j) {
      unsigned short h;
      h = f2bf(va[j]);      ah0[j] = (short)h; al0[j] = (short)f2bf(va[j] - bf2f(h));
      h = f2bf(va[j + 8]);  ah1[j] = (short)h; al1[j] = (short)f2bf(va[j + 8] - bf2f(h));
      h = f2bf(vb[j]);      bh0[j] = (short)h; bl0[j] = (short)f2bf(vb[j] - bf2f(h));
      h = f2bf(vb[j + 8]);  bh1[j] = (short)h; bl1[j] = (short)f2bf(vb[j + 8] - bf2f(h));
    }
    int kg = ks >> 3;  // 0 or 2
    *reinterpret_cast<s16x8*>(&aH[((kg + 0) * 128 + sm) * 8]) = ah0;
    *reinterpret_cast<s16x8*>(&aH[((kg + 1) * 128 + sm) * 8]) = ah1;
    *reinterpret_cast<s16x8*>(&aL[((kg + 0) * 128 + sm) * 8]) = al0;
    *reinterpret_cast<s16x8*>(&aL[((kg + 1) * 128 + sm) * 8]) = al1;
    *reinterpret_cast<s16x8*>(&bHs[((kg + 0) * 128 + sm) * 8]) = bh0;
    *reinterpret_cast<s16x8*>(&bHs[((kg + 1) * 128 + sm) * 8]) = bh1;
    *reinterpret_cast<s16x8*>(&bLs[((kg + 0) * 128 + sm) * 8]) = bl0;
    *reinterpret_cast<s16x8*>(&bLs[((kg + 1) * 128 + sm) * 8]) = bl1;
    __syncthreads();
    // ---- fragments + MFMA ----
    s16x8 afH[4], afL[4], bfH[4], bfL[4];
#pragma unroll
    for (int mi = 0; mi < 4; ++mi) {
      int eo = (g * 128 + (wr * 64 + mi * 16 + c)) * 8;
      afH[mi] = *reinterpret_cast<const s16x8*>(&aH[eo]);
      afL[mi] = *reinterpret_cast<const s16x8*>(&aL[eo]);
    }
#pragma unroll
    for (int ni = 0; ni < 4; ++ni) {
      int eo = (g * 128 + (wc * 64 + ni * 16 + c)) * 8;
      bfH[ni] = *reinterpret_cast<const s16x8*>(&bHs[eo]);
      bfL[ni] = *reinterpret_cast<const s16x8*>(&bLs[eo]);
    }
#pragma unroll
    for (int mi = 0; mi < 4; ++mi)
#pragma unroll
      for (int ni = 0; ni < 4; ++ni) {
        acc[mi][ni] = __builtin_amdgcn_mfma_f32_16x16x32_bf16(afH[mi], bfH[ni], acc[mi][ni], 0, 0, 0);
        acc[mi][ni] = __builtin_amdgcn_mfma_f32_16x16x32_bf16(afH[mi], bfL[ni], acc[mi][ni], 0, 0, 0);
        acc[mi][ni] = __builtin_amdgcn_mfma_f32_16x16x32_bf16(afL[mi], bfH[ni], acc[mi][ni], 0, 0, 0);
      }
    __syncthreads();
  }

  // ---- epilogue: C/D layout col = lane&15, row = (lane>>4)*4 + reg ----
#pragma unroll
  for (int mi = 0; mi < 4; ++mi) {
#pragma unroll
    for (int ni = 0; ni < 4; ++ni) {
#pragma unroll
      for (int r = 0; r < 4; ++r) {
        int R = row0 + wr * 64 + mi * 16 + g * 4 + r;
        int Cc = col0 + wc * 64 + ni * 16 + c;
        if (R < M && Cc < Nc) {
          float v = acc[mi][ni][r];
          if (mode == 1) {
            float d2 = sqb[R] + sqb[Cc] - 2.f * v;
            C[(long long)R * ldc + Cc] = (R == Cc) ? 0.f : expf(-d2);
          } else {
            float o = alpha * v;
            if (D) o += beta * D[(long long)R * ldd + Cc];
            C[(long long)R * ldc + Cc] = o;
          }
        }
      }
    }
  }
}

// ---------------- reductions / pool / FC ----------------

static __global__ void sumsq_kernel(const float* __restrict__ src, long long n, float* out) {
  float s = 0.f;
  long long i = (long long)blockIdx.x * blockDim.x + threadIdx.x;
  long long st = (long long)gridDim.x * blockDim.x;
  for (; i < n; i += st) { float v = src[i]; s += v * v; }
  __shared__ float red[256];
  red[threadIdx.x] = s;
  __syncthreads();
  for (int stp = 128; stp > 0; stp >>= 1) {
    if (threadIdx.x < stp) red[threadIdx.x] += red[threadIdx.x + stp];
    __syncthreads();
  }
  if (threadIdx.x == 0) atomicAdd(out, red[0]);
}

static __global__ void maxpool_kernel(const float* __restrict__ H, float* g, int N, int F, int total) {
  int idx = blockIdx.x * blockDim.x + threadIdx.x;
  if (idx >= total) return;
  int b = idx / F, f = idx - b * F;
  const float* hb = H + (long long)b * N * F + f;
  float m = -INFINITY;
  for (int n = 0; n < N; ++n) m = fmaxf(m, hb[(long long)n * F]);
  g[idx] = m;
}

static __global__ void fc_kernel(const float* __restrict__ in, const float* __restrict__ W,
                                 const float* __restrict__ bias, float* out,
                                 int Bc, int K, int J, int do_relu) {
  int gtid = blockIdx.x * blockDim.x + threadIdx.x;
  int wid = gtid >> 6;
  int lane = gtid & 63;
  if (wid >= Bc * J) return;
  int b = wid / J, j = wid - b * J;
  const float* ib = in + (long long)b * K;
  const float* wj = W + (long long)j * K;
  float s = 0.f;
  for (int k = lane; k < K; k += 64) s += ib[k] * wj[k];
  for (int off = 32; off > 0; off >>= 1) s += __shfl_down(s, off);
  if (lane == 0) {
    s += bias[j];
    out[wid] = do_relu ? fmaxf(s, 0.f) : s;
  }
}

static __global__ void finalize_kernel(const float* scal, float* out_regs) {
  if (threadIdx.x == 0 && blockIdx.x == 0) {
    float r1 = sqrtf(scal[0]), r2 = sqrtf(scal[1]), r3 = sqrtf(scal[2]);
    float nw = sqrtf(scal[3]), nb = sqrtf(scal[4]);
    out_regs[0] = r1; out_regs[1] = r2; out_regs[2] = r3;
    out_regs[3] = nw; out_regs[4] = nb;
    out_regs[5] = nw; out_regs[6] = nb;
    out_regs[7] = nw; out_regs[8] = nb;
  }
}

// ---------------- host orchestration ----------------

extern "C" void kernel_launch(void* const* d_in, const int* in_sizes, int n_in,
                              void* d_out, int out_size, void* d_ws, size_t ws_size,
                              hipStream_t stream) {
  const float* x   = (const float*)d_in[0];
  const float* w1  = (const float*)d_in[4];
  const float* b1  = (const float*)d_in[5];
  const float* w2  = (const float*)d_in[6];
  const float* b2  = (const float*)d_in[7];
  const float* w3  = (const float*)d_in[8];
  const float* b3  = (const float*)d_in[9];
  const float* fw1 = (const float*)d_in[10];
  const float* fb1 = (const float*)d_in[11];
  const float* fw2 = (const float*)d_in[12];
  const float* fb2 = (const float*)d_in[13];
  const float* fw3 = (const float*)d_in[14];
  const float* fb3 = (const float*)d_in[15];
  float* out = (float*)d_out;

  const long long NN = (long long)N_ * N_;

  auto footprint = [&](int G) -> unsigned long long {
    unsigned long long f = 0;
    f += (unsigned long long)G * NN;          // L4
    f += (unsigned long long)G * N_ * 512 * 3; // Ta, Tb, TT
    f += (unsigned long long)G * N_ * (128 + 512 + 1024); // H1c,H2c,H3c
    f += (unsigned long long)G * N_ * 1024 * 2;  // HcT, LHT
    f += 3ULL * 512 * 1024;                   // WT
    f += 128ULL*128 + 512ULL*512 + 1024ULL*1024; // Mm1..3
    f += (unsigned long long)G * N_ * 2;      // sq, dinv
    f += (unsigned long long)B_ * (1024 + 512 + 128) + 64;
    return f * 4ULL;
  };
  int G = 4;
  while (G > 1 && footprint(G) > ws_size) G >>= 1;
  if (footprint(G) > ws_size) return;

  float* ws = (float*)d_ws;
  long long off = 0;
  float* L4  = ws + off; off += (long long)G * NN;
  float* Ta  = ws + off; off += (long long)G * N_ * 512;
  float* Tb  = ws + off; off += (long long)G * N_ * 512;
  float* TT  = ws + off; off += (long long)G * N_ * 512;
  float* H1c = ws + off; off += (long long)G * N_ * 128;
  float* H2c = ws + off; off += (long long)G * N_ * 512;
  float* H3c = ws + off; off += (long long)G * N_ * 1024;
  float* HcT = ws + off; off += (long long)G * N_ * 1024;
  float* LHT = ws + off; off += (long long)G * N_ * 1024;
  float* WT  = ws + off; off += 3LL * 512 * 1024;
  float* Mm1 = ws + off; off += 128 * 128;
  float* Mm2 = ws + off; off += 512 * 512;
  float* Mm3 = ws + off; off += 1024 * 1024;
  float* sq  = ws + off; off += (long long)G * N_;
  float* dinv= ws + off; off += (long long)G * N_;
  float* gb  = ws + off; off += (long long)B_ * 1024;
  float* o1  = ws + off; off += (long long)B_ * 512;
  float* o2  = ws + off; off += (long long)B_ * 128;
  float* scal= ws + off; off += 16;

  const long long GN = (long long)G * N_;

  auto gemm = [&](const float* A, int lda, long long sA,
                  const float* BT, int ldb, long long sB,
                  const float* D, int ldd, long long sD,
                  float* C, int ldc, long long sC,
                  int M, int K, int Nc, int nb,
                  float alpha, float beta, int mode, const float* sqp, long long sSq) {
    dim3 grid((Nc + 127) / 128, (M + 127) / 128, nb);
    gemm_mf<<<grid, 256, 0, stream>>>(A, lda, sA, BT, ldb, sB, D, ldd, sD,
                                      C, ldc, sC, M, K, Nc, alpha, beta, mode, sqp, sSq);
  };
  auto transpose = [&](const float* src, float* dst, int R, int Cc, long long sS, long long sD2, int nb) {
    dim3 grid((Cc + 31) / 32, (R + 31) / 32, nb);
    transpose_f32<<<grid, dim3(32, 8), 0, stream>>>(src, dst, R, Cc, sS, sD2);
  };

  zerof_kernel<<<1, 256, 0, stream>>>(scal, 16);
  zerof_kernel<<<64, 256, 0, stream>>>(Mm1, 128LL * 128);
  zerof_kernel<<<256, 256, 0, stream>>>(Mm2, 512LL * 512);
  zerof_kernel<<<1024, 256, 0, stream>>>(Mm3, 1024LL * 1024);

  auto layer = [&](const float* X, int Fin, const float* W, const float* bias,
                   int taps, int Fout, float* Hc, float* Mm) {
    const long long NFi = (long long)N_ * Fin;
    const long long NFo = (long long)N_ * Fout;
    // graph -> L4 (fused exp epilogue, diag=0)
    rowsq_kernel<<<(int)GN, 256, 0, stream>>>(X, sq, Fin);
    gemm(X, Fin, NFi, X, Fin, NFi, nullptr, 0, 0, L4, N_, NN,
         N_, Fin, N_, G, 1.f, 0.f, 1, sq, N_);
    rowsum_dinv_kernel<<<(int)GN, 256, 0, stream>>>(L4, dinv, N_);
    scaleL_kernel<<<4096, 256, 0, stream>>>(L4, dinv, N_, (long long)G * NN);
    // W^T for all taps
    transpose(W, WT, Fin, Fout, (long long)Fin * Fout, (long long)Fin * Fout, taps);
    // tap 0: Hc = X @ W0
    gemm(X, Fin, 0, WT, Fin, 0, nullptr, 0, 0, Hc, Fout, 0,
         (int)GN, Fin, Fout, 1, 1.f, 0.f, 0, nullptr, 0);
    if (taps > 1) {
      // T1 = L @ X
      transpose(X, TT, (int)GN, Fin, 0, 0, 1);
      gemm(L4, N_, NN, TT, (int)GN, N_, nullptr, 0, 0, Ta, Fin, NFi,
           N_, N_, Fin, G, 1.f, 0.f, 0, nullptr, 0);
      gemm(Ta, Fin, 0, WT + (long long)Fout * Fin, Fin, 0, Hc, Fout, 0, Hc, Fout, 0,
           (int)GN, Fin, Fout, 1, 1.f, 1.f, 0, nullptr, 0);
      const float* prev2 = X;
      float* prev1 = Ta;
      for (int k = 2; k < taps; ++k) {
        transpose(prev1, TT, (int)GN, Fin, 0, 0, 1);
        float* dst = (k == 2) ? Tb : (float*)prev2;
        gemm(L4, N_, NN, TT, (int)GN, N_, prev2, Fin, NFi, dst, Fin, NFi,
             N_, N_, Fin, G, 2.f, -1.f, 0, nullptr, 0);
        gemm(dst, Fin, 0, WT + (long long)k * Fout * Fin, Fin, 0, Hc, Fout, 0, Hc, Fout, 0,
             (int)GN, Fin, Fout, 1, 1.f, 1.f, 0, nullptr, 0);
        prev2 = prev1; prev1 = dst;
      }
    }
    bias_relu_kernel<<<4096, 256, 0, stream>>>(Hc, bias, GN * Fout, Fout);
    // regularizer: LHT = H^T L + H^T ; Mm += HcT @ LHT^T
    transpose(Hc, HcT, (int)GN, Fout, 0, 0, 1);
    gemm(HcT, (int)GN, N_, L4, N_, NN, HcT, (int)GN, N_, LHT, (int)GN, N_,
         Fout, N_, N_, G, 1.f, 1.f, 0, nullptr, 0);
    gemm(HcT, (int)GN, 0, LHT, (int)GN, 0, Mm, Fout, 0, Mm, Fout, 0,
         Fout, (int)GN, Fout, 1, 1.f, 1.f, 0, nullptr, 0);
  };

  for (int c = 0; c < B_ / G; ++c) {
    const float* Xc = x + (long long)c * GN * 6;
    layer(Xc,  6,   w1, b1, 6, 128,  H1c, Mm1);
    layer(H1c, 128, w2, b2, 5, 512,  H2c, Mm2);
    layer(H2c, 512, w3, b3, 3, 1024, H3c, Mm3);
    maxpool_kernel<<<(G * 1024 + 255) / 256, 256, 0, stream>>>(
        H3c, gb + (long long)c * G * 1024, N_, 1024, G * 1024);
  }

  sumsq_kernel<<<64, 256, 0, stream>>>(Mm1, 128LL * 128, scal + 0);
  sumsq_kernel<<<256, 256, 0, stream>>>(Mm2, 512LL * 512, scal + 1);
  sumsq_kernel<<<256, 256, 0, stream>>>(Mm3, 1024LL * 1024, scal + 2);

  fc_kernel<<<(B_ * 512 * 64 + 255) / 256, 256, 0, stream>>>(gb, fw1, fb1, o1, B_, 1024, 512, 1);
  fc_kernel<<<(B_ * 128 * 64 + 255) / 256, 256, 0, stream>>>(o1, fw2, fb2, o2, B_, 512, 128, 1);
  fc_kernel<<<(B_ * 10 * 64 + 255) / 256, 256, 0, stream>>>(o2, fw3, fb3, out, B_, 128, 10, 0);

  sumsq_kernel<<<256, 256, 0, stream>>>(fw1, 512LL * 1024, scal + 3);
  sumsq_kernel<<<1, 256, 0, stream>>>(fb1, 512LL, scal + 4);
  finalize_kernel<<<1, 64, 0, stream>>>(scal, out + 160);
}

// Round 5
// 15295.862 us; speedup vs baseline: 1.9651x; 1.1860x over previous
//
#include <hip/hip_runtime.h>

#define B_ 16
#define N_ 2048

typedef __attribute__((ext_vector_type(8))) short s16x8;
typedef __attribute__((ext_vector_type(4))) float f32x4;

__device__ inline unsigned short f2bf(float f) {
  unsigned u = __float_as_uint(f);
  u += 0x7FFFu + ((u >> 16) & 1u);
  return (unsigned short)(u >> 16);
}
__device__ inline float bf2f(unsigned short h) {
  return __uint_as_float(((unsigned)h) << 16);
}
__device__ inline s16x8 zero8() {
  s16x8 v;
#pragma unroll
  for (int i = 0; i < 8; ++i) v[i] = 0;
  return v;
}

// ---------------- small utility kernels ----------------

static __global__ void zerof_kernel(float* p, long long n) {
  long long i = (long long)blockIdx.x * blockDim.x + threadIdx.x;
  long long st = (long long)gridDim.x * blockDim.x;
  for (; i < n; i += st) p[i] = 0.f;
}

static __global__ void rowsq_kernel(const float* __restrict__ X, float* __restrict__ sq, int F) {
  int row = blockIdx.x;
  const float* xr = X + (long long)row * F;
  float s = 0.f;
  for (int f = threadIdx.x; f < F; f += blockDim.x) { float v = xr[f]; s += v * v; }
  __shared__ float red[256];
  red[threadIdx.x] = s;
  __syncthreads();
  for (int st = 128; st > 0; st >>= 1) {
    if (threadIdx.x < st) red[threadIdx.x] += red[threadIdx.x + st];
    __syncthreads();
  }
  if (threadIdx.x == 0) sq[row] = red[0];
}

static __global__ void rowsum_dinv_kernel(const float* __restrict__ A, float* __restrict__ dinv, int N) {
  long long row = blockIdx.x;
  const float* ar = A + row * N;
  float s = 0.f;
  for (int j = threadIdx.x; j < N; j += blockDim.x) s += ar[j];
  __shared__ float red[256];
  red[threadIdx.x] = s;
  __syncthreads();
  for (int st = 128; st > 0; st >>= 1) {
    if (threadIdx.x < st) red[threadIdx.x] += red[threadIdx.x + st];
    __syncthreads();
  }
  if (threadIdx.x == 0) {
    float d = red[0];
    dinv[row] = (d > 0.f) ? rsqrtf(d) : 0.f;
  }
}

static __global__ void bias_relu_kernel(float* H, const float* __restrict__ bias, long long total, int F) {
  long long i = (long long)blockIdx.x * blockDim.x + threadIdx.x;
  long long st = (long long)gridDim.x * blockDim.x;
  for (; i < total; i += st) {
    int f = (int)(i % F);
    H[i] = fmaxf(H[i] + bias[f], 0.f);
  }
}

// row-major convert: planes[r][c] = hi/lo of src[r*lds+c]
static __global__ void cvt_rm_kernel(const float* __restrict__ src, int lds,
                                     short* __restrict__ dh, short* __restrict__ dl,
                                     int ldd, long long R, int Cc) {
  long long total = R * Cc;
  long long i = (long long)blockIdx.x * blockDim.x + threadIdx.x;
  long long st = (long long)gridDim.x * blockDim.x;
  for (; i < total; i += st) {
    long long r = i / Cc; int c = (int)(i - r * Cc);
    float v = src[r * lds + c];
    unsigned short h = f2bf(v);
    dh[r * ldd + c] = (short)h;
    dl[r * ldd + c] = (short)f2bf(v - bf2f(h));
  }
}

// transposed convert: planes[c][r] = hi/lo of src[r*lds+c] (per z)
static __global__ void cvt_tr_kernel(const float* __restrict__ src, int lds, long long sS,
                                     short* __restrict__ dh, short* __restrict__ dl,
                                     int ldd, long long sD, int R, int Cc) {
  int z = blockIdx.z;
  src += (long long)z * sS;
  dh += (long long)z * sD;
  dl += (long long)z * sD;
  __shared__ float tile[32][33];
  int r0 = blockIdx.y * 32, c0 = blockIdx.x * 32;
  int tx = threadIdx.x, ty = threadIdx.y;
#pragma unroll
  for (int i = 0; i < 32; i += 8) {
    int r = r0 + ty + i, cx = c0 + tx;
    tile[ty + i][tx] = (r < R && cx < Cc) ? src[(long long)r * lds + cx] : 0.f;
  }
  __syncthreads();
#pragma unroll
  for (int i = 0; i < 32; i += 8) {
    int cr = c0 + ty + i, rx = r0 + tx;
    if (cr < Cc && rx < R) {
      float v = tile[tx][ty + i];
      unsigned short h = f2bf(v);
      dh[(long long)cr * ldd + rx] = (short)h;
      dl[(long long)cr * ldd + rx] = (short)f2bf(v - bf2f(h));
    }
  }
}

// L planes = hi/lo of (-A[i]*dinv_r*dinv_j)
static __global__ void cvt_scaleL_kernel(const float* __restrict__ A, const float* __restrict__ dinv,
                                         short* __restrict__ dh, short* __restrict__ dl,
                                         int N, long long total) {
  long long i = (long long)blockIdx.x * blockDim.x + threadIdx.x;
  long long st = (long long)gridDim.x * blockDim.x;
  for (; i < total; i += st) {
    long long bn = i / N; int j = (int)(i - bn * N);
    long long b = bn / N; int r = (int)(bn - b * N);
    float v = -A[i] * dinv[b * N + r] * dinv[b * N + j];
    unsigned short h = f2bf(v);
    dh[i] = (short)h;
    dl[i] = (short)f2bf(v - bf2f(h));
  }
}

static __global__ void pad0_kernel(short* ph, short* pl, int ld, long long R, int c0, int c1) {
  int w = c1 - c0;
  long long total = R * w;
  long long i = (long long)blockIdx.x * blockDim.x + threadIdx.x;
  long long st = (long long)gridDim.x * blockDim.x;
  for (; i < total; i += st) {
    long long r = i / w; int c = c0 + (int)(i - r * w);
    ph[r * ld + c] = 0;
    pl[r * ld + c] = 0;
  }
}

static __global__ void initC_kernel(float* C, int ldc, const float* D, int ldd,
                                    long long R, int Cc, float beta) {
  long long total = R * Cc;
  long long i = (long long)blockIdx.x * blockDim.x + threadIdx.x;
  long long st = (long long)gridDim.x * blockDim.x;
  for (; i < total; i += st) {
    long long r = i / Cc; int c = (int)(i - r * Cc);
    C[r * ldc + c] = D ? beta * D[r * ldd + c] : 0.f;
  }
}

// f32 transpose (for HcT): dst[c][r] = src[r][c]
static __global__ void transpose_f32(const float* __restrict__ src, float* __restrict__ dst,
                                     int R, int Cc) {
  __shared__ float tile[32][33];
  int r0 = blockIdx.y * 32, c0 = blockIdx.x * 32;
  int tx = threadIdx.x, ty = threadIdx.y;
#pragma unroll
  for (int i = 0; i < 32; i += 8) {
    int r = r0 + ty + i, cx = c0 + tx;
    tile[ty + i][tx] = (r < R && cx < Cc) ? src[(long long)r * Cc + cx] : 0.f;
  }
  __syncthreads();
#pragma unroll
  for (int i = 0; i < 32; i += 8) {
    int cr = c0 + ty + i, rx = r0 + tx;
    if (cr < Cc && rx < R) dst[(long long)cr * R + rx] = tile[tx][ty + i];
  }
}

// ---------------- MFMA split-bf16 GEMM (plane inputs) ----------------
// acc = A(MxK) * BT(NcxK)^T over k in this split's range.
// mode 0: C = alpha*acc + beta*D
// mode 1: graph: C = (r==c) ? 0 : exp(-(sq_r+sq_c-2*acc))
// mode 2: atomicAdd(C, alpha*acc)
// mode 3: planes Ch/Cl = split(alpha*acc + beta*D)
static __global__ __launch_bounds__(256) void gemm_mf(
    const short* __restrict__ Ah, const short* __restrict__ Al, int lda, long long sA,
    const short* __restrict__ Bh, const short* __restrict__ Bl, int ldb, long long sB,
    const float* D, int ldd, long long sD,
    float* C, short* Ch, short* Cl, int ldc, long long sC,
    int M, int K, int Nc,
    float alpha, float beta,
    int mode, const float* sqp, long long sSq, int ksplit) {
  int bz = blockIdx.z;
  int zb = bz / ksplit, zk = bz - zb * ksplit;
  Ah += (long long)zb * sA; Al += (long long)zb * sA;
  Bh += (long long)zb * sB; Bl += (long long)zb * sB;
  if (C) C += (long long)zb * sC;
  if (Ch) { Ch += (long long)zb * sC; Cl += (long long)zb * sC; }
  if (D) D += (long long)zb * sD;
  const float* sqb = sqp ? sqp + (long long)zb * sSq : nullptr;

  int k_begin = 0, k_end = K;
  if (ksplit > 1) {
    int kslice = (((K / ksplit) + 31) >> 5) << 5;
    k_begin = zk * kslice;
    k_end = min(K, k_begin + kslice);
  }

  __shared__ __align__(16) short aH[4096], aL[4096], bH[4096], bL[4096];

  int row0 = blockIdx.y * 128, col0 = blockIdx.x * 128;
  int t = threadIdx.x;
  int w = t >> 6, l = t & 63, g = l >> 4, c = l & 15;
  int wr = w >> 1, wc = w & 1;

  f32x4 acc[4][4];
#pragma unroll
  for (int i = 0; i < 4; ++i)
#pragma unroll
    for (int j = 0; j < 4; ++j) {
      acc[i][j][0] = 0.f; acc[i][j][1] = 0.f; acc[i][j][2] = 0.f; acc[i][j][3] = 0.f;
    }

  int sm = t >> 1;
  int ks = (t & 1) << 4;
  int arow = row0 + sm;
  int brow = col0 + sm;

  for (int k0 = k_begin; k0 < k_end; k0 += 32) {
    s16x8 a0, a1, a2, a3, b0, b1, b2, b3;
    if (arow < M) {
      long long base = (long long)arow * lda + k0 + ks;
      a0 = *reinterpret_cast<const s16x8*>(Ah + base);
      a1 = *reinterpret_cast<const s16x8*>(Ah + base + 8);
      a2 = *reinterpret_cast<const s16x8*>(Al + base);
      a3 = *reinterpret_cast<const s16x8*>(Al + base + 8);
    } else { a0 = zero8(); a1 = zero8(); a2 = zero8(); a3 = zero8(); }
    if (brow < Nc) {
      long long base = (long long)brow * ldb + k0 + ks;
      b0 = *reinterpret_cast<const s16x8*>(Bh + base);
      b1 = *reinterpret_cast<const s16x8*>(Bh + base + 8);
      b2 = *reinterpret_cast<const s16x8*>(Bl + base);
      b3 = *reinterpret_cast<const s16x8*>(Bl + base + 8);
    } else { b0 = zero8(); b1 = zero8(); b2 = zero8(); b3 = zero8(); }
    int kg = ks >> 3;
    *reinterpret_cast<s16x8*>(&aH[((kg + 0) * 128 + sm) * 8]) = a0;
    *reinterpret_cast<s16x8*>(&aH[((kg + 1) * 128 + sm) * 8]) = a1;
    *reinterpret_cast<s16x8*>(&aL[((kg + 0) * 128 + sm) * 8]) = a2;
    *reinterpret_cast<s16x8*>(&aL[((kg + 1) * 128 + sm) * 8]) = a3;
    *reinterpret_cast<s16x8*>(&bH[((kg + 0) * 128 + sm) * 8]) = b0;
    *reinterpret_cast<s16x8*>(&bH[((kg + 1) * 128 + sm) * 8]) = b1;
    *reinterpret_cast<s16x8*>(&bL[((kg + 0) * 128 + sm) * 8]) = b2;
    *reinterpret_cast<s16x8*>(&bL[((kg + 1) * 128 + sm) * 8]) = b3;
    __syncthreads();
    s16x8 afH[4], afL[4], bfH[4], bfL[4];
#pragma unroll
    for (int mi = 0; mi < 4; ++mi) {
      int eo = (g * 128 + (wr * 64 + mi * 16 + c)) * 8;
      afH[mi] = *reinterpret_cast<const s16x8*>(&aH[eo]);
      afL[mi] = *reinterpret_cast<const s16x8*>(&aL[eo]);
    }
#pragma unroll
    for (int ni = 0; ni < 4; ++ni) {
      int eo = (g * 128 + (wc * 64 + ni * 16 + c)) * 8;
      bfH[ni] = *reinterpret_cast<const s16x8*>(&bH[eo]);
      bfL[ni] = *reinterpret_cast<const s16x8*>(&bL[eo]);
    }
#pragma unroll
    for (int mi = 0; mi < 4; ++mi)
#pragma unroll
      for (int ni = 0; ni < 4; ++ni) {
        acc[mi][ni] = __builtin_amdgcn_mfma_f32_16x16x32_bf16(afH[mi], bfH[ni], acc[mi][ni], 0, 0, 0);
        acc[mi][ni] = __builtin_amdgcn_mfma_f32_16x16x32_bf16(afH[mi], bfL[ni], acc[mi][ni], 0, 0, 0);
        acc[mi][ni] = __builtin_amdgcn_mfma_f32_16x16x32_bf16(afL[mi], bfH[ni], acc[mi][ni], 0, 0, 0);
      }
    __syncthreads();
  }

#pragma unroll
  for (int mi = 0; mi < 4; ++mi) {
#pragma unroll
    for (int ni = 0; ni < 4; ++ni) {
#pragma unroll
      for (int r = 0; r < 4; ++r) {
        int R = row0 + wr * 64 + mi * 16 + g * 4 + r;
        int Cc2 = col0 + wc * 64 + ni * 16 + c;
        if (R < M && Cc2 < Nc) {
          float v = acc[mi][ni][r];
          long long idx = (long long)R * ldc + Cc2;
          if (mode == 1) {
            float d2 = sqb[R] + sqb[Cc2] - 2.f * v;
            C[idx] = (R == Cc2) ? 0.f : expf(-d2);
          } else if (mode == 2) {
            atomicAdd(&C[idx], alpha * v);
          } else {
            float o = alpha * v;
            if (D) o += beta * D[(long long)R * ldd + Cc2];
            if (mode == 3) {
              unsigned short h = f2bf(o);
              Ch[idx] = (short)h;
              Cl[idx] = (short)f2bf(o - bf2f(h));
            } else {
              C[idx] = o;
            }
          }
        }
      }
    }
  }
}

// ---------------- reductions / pool / FC ----------------

static __global__ void sumsq_kernel(const float* __restrict__ src, long long n, float* out) {
  float s = 0.f;
  long long i = (long long)blockIdx.x * blockDim.x + threadIdx.x;
  long long st = (long long)gridDim.x * blockDim.x;
  for (; i < n; i += st) { float v = src[i]; s += v * v; }
  __shared__ float red[256];
  red[threadIdx.x] = s;
  __syncthreads();
  for (int stp = 128; stp > 0; stp >>= 1) {
    if (threadIdx.x < stp) red[threadIdx.x] += red[threadIdx.x + stp];
    __syncthreads();
  }
  if (threadIdx.x == 0) atomicAdd(out, red[0]);
}

static __global__ void maxpool_kernel(const float* __restrict__ H, float* g, int N, int F, int total) {
  int idx = blockIdx.x * blockDim.x + threadIdx.x;
  if (idx >= total) return;
  int b = idx / F, f = idx - b * F;
  const float* hb = H + (long long)b * N * F + f;
  float m = -INFINITY;
  for (int n = 0; n < N; ++n) m = fmaxf(m, hb[(long long)n * F]);
  g[idx] = m;
}

static __global__ void fc_kernel(const float* __restrict__ in, const float* __restrict__ W,
                                 const float* __restrict__ bias, float* out,
                                 int Bc, int K, int J, int do_relu) {
  int gtid = blockIdx.x * blockDim.x + threadIdx.x;
  int wid = gtid >> 6;
  int lane = gtid & 63;
  if (wid >= Bc * J) return;
  int b = wid / J, j = wid - b * J;
  const float* ib = in + (long long)b * K;
  const float* wj = W + (long long)j * K;
  float s = 0.f;
  for (int k = lane; k < K; k += 64) s += ib[k] * wj[k];
  for (int off = 32; off > 0; off >>= 1) s += __shfl_down(s, off);
  if (lane == 0) {
    s += bias[j];
    out[wid] = do_relu ? fmaxf(s, 0.f) : s;
  }
}

static __global__ void finalize_kernel(const float* scal, float* out_regs) {
  if (threadIdx.x == 0 && blockIdx.x == 0) {
    float r1 = sqrtf(scal[0]), r2 = sqrtf(scal[1]), r3 = sqrtf(scal[2]);
    float nw = sqrtf(scal[3]), nb = sqrtf(scal[4]);
    out_regs[0] = r1; out_regs[1] = r2; out_regs[2] = r3;
    out_regs[3] = nw; out_regs[4] = nb;
    out_regs[5] = nw; out_regs[6] = nb;
    out_regs[7] = nw; out_regs[8] = nb;
  }
}

// ---------------- host orchestration ----------------

struct Ptrs {
  float *L4f, *Tcf, *Hc1, *Hc2, *Hc3, *HcTf;
  float *Mm1, *Mm2, *Mm3, *sq, *dinv, *gb, *o1, *o2, *scal;
  short *Lh, *Ll, *Tch, *Tcl, *TTh, *TTl, *Xgh, *Xgl, *HTh, *HTl, *LHh, *LHl;
  short *W1h, *W1l, *W2h, *W2l, *W3h, *W3l;
};

extern "C" void kernel_launch(void* const* d_in, const int* in_sizes, int n_in,
                              void* d_out, int out_size, void* d_ws, size_t ws_size,
                              hipStream_t stream) {
  const float* x   = (const float*)d_in[0];
  const float* w1  = (const float*)d_in[4];
  const float* b1  = (const float*)d_in[5];
  const float* w2  = (const float*)d_in[6];
  const float* b2  = (const float*)d_in[7];
  const float* w3  = (const float*)d_in[8];
  const float* b3  = (const float*)d_in[9];
  const float* fw1 = (const float*)d_in[10];
  const float* fb1 = (const float*)d_in[11];
  const float* fw2 = (const float*)d_in[12];
  const float* fb2 = (const float*)d_in[13];
  const float* fw3 = (const float*)d_in[14];
  const float* fb3 = (const float*)d_in[15];
  float* out = (float*)d_out;

  float* ws = (float*)d_ws;
  const long long NN = (long long)N_ * N_;

  Ptrs p;
  auto layout = [&](int G) -> unsigned long long {
    long long off = 0;
    auto aF = [&](long long n) { float* q = ws + off; off += (n + 7) & ~7LL; return q; };
    auto aS = [&](long long n) { short* q = (short*)(ws + off); off += (((n + 1) >> 1) + 7) & ~7LL; return q; };
    long long GN = (long long)G * N_;
    p.L4f = aF(G * NN);
    p.Lh = aS(G * NN); p.Ll = aS(G * NN);
    p.Tcf = aF(GN * 1536);
    p.Tch = aS(GN * 1536); p.Tcl = aS(GN * 1536);
    p.TTh = aS(GN * 512); p.TTl = aS(GN * 512);
    p.Xgh = aS(GN * 32); p.Xgl = aS(GN * 32);
    p.Hc1 = aF(GN * 128); p.Hc2 = aF(GN * 512); p.Hc3 = aF(GN * 1024);
    p.HcTf = aF(GN * 1024);
    p.HTh = aS(GN * 1024); p.HTl = aS(GN * 1024);
    p.LHh = aS(GN * 1024); p.LHl = aS(GN * 1024);
    p.W1h = aS(128 * 64); p.W1l = aS(128 * 64);
    p.W2h = aS(512 * 640); p.W2l = aS(512 * 640);
    p.W3h = aS(1024 * 1536); p.W3l = aS(1024 * 1536);
    p.Mm1 = aF(128 * 128); p.Mm2 = aF(512 * 512); p.Mm3 = aF(1024 * 1024);
    p.sq = aF(GN); p.dinv = aF(GN);
    p.gb = aF(B_ * 1024); p.o1 = aF(B_ * 512); p.o2 = aF(B_ * 128);
    p.scal = aF(16);
    return (unsigned long long)off * 4ULL;
  };
  int G = 4;
  while (G > 1 && layout(G) > ws_size) G >>= 1;
  if (layout(G) > ws_size) return;
  layout(G);  // final pointer assignment

  const long long GN = (long long)G * N_;
  auto blk1d = [](long long n) { return (int)(((n + 255) / 256 < 4096) ? (n + 255) / 256 : 4096); };

  // ---- W plane conversions (chunk-invariant) ----
  {
    // taps z: src w+z*Fin*Fout (Fin x Fout) -> dst (Fout x Kpad) at col z*Fin
    cvt_tr_kernel<<<dim3(4, 1, 6), dim3(32, 8), 0, stream>>>(
        w1, 128, 6LL * 128, p.W1h, p.W1l, 64, 6, 6, 128);
    pad0_kernel<<<blk1d(128LL * 28), 256, 0, stream>>>(p.W1h, p.W1l, 64, 128, 36, 64);
    cvt_tr_kernel<<<dim3(16, 4, 5), dim3(32, 8), 0, stream>>>(
        w2, 512, 128LL * 512, p.W2h, p.W2l, 640, 128, 128, 512);
    cvt_tr_kernel<<<dim3(32, 16, 3), dim3(32, 8), 0, stream>>>(
        w3, 1024, 512LL * 1024, p.W3h, p.W3l, 1536, 512, 512, 1024);
    pad0_kernel<<<blk1d(GN * 26), 256, 0, stream>>>(p.Xgh, p.Xgl, 32, GN, 6, 32);
  }

  zerof_kernel<<<1, 256, 0, stream>>>(p.scal, 16);
  zerof_kernel<<<64, 256, 0, stream>>>(p.Mm1, 128LL * 128);
  zerof_kernel<<<256, 256, 0, stream>>>(p.Mm2, 512LL * 512);
  zerof_kernel<<<1024, 256, 0, stream>>>(p.Mm3, 1024LL * 1024);

  auto do_layer = [&](const float* X, int Fin, int taps, int Fout,
                      const float* bias, const short* Wh, const short* Wl, int Kpad,
                      float* Hc, float* Mm) {
    int Ktot = taps * Fin;
    // T0 conversion into Tcat planes + transposed planes
    cvt_rm_kernel<<<blk1d(GN * Fin), 256, 0, stream>>>(X, Fin, p.Tch, p.Tcl, Kpad, GN, Fin);
    cvt_tr_kernel<<<dim3((Fin + 31) / 32, 64, G), dim3(32, 8), 0, stream>>>(
        X, Fin, (long long)N_ * Fin, p.TTh, p.TTl, N_, (long long)Fin * N_, N_, Fin);
    const short *Gah, *Gal; int Glda, GK;
    if (Fin == 6) {
      cvt_rm_kernel<<<blk1d(GN * 6), 256, 0, stream>>>(X, 6, p.Xgh, p.Xgl, 32, GN, 6);
      pad0_kernel<<<blk1d(GN * (Kpad - Ktot)), 256, 0, stream>>>(p.Tch, p.Tcl, Kpad, GN, Ktot, Kpad);
      Gah = p.Xgh; Gal = p.Xgl; Glda = 32; GK = 32;
    } else {
      Gah = p.Tch; Gal = p.Tcl; Glda = Kpad; GK = Fin;
    }
    rowsq_kernel<<<(int)GN, 256, 0, stream>>>(X, p.sq, Fin);
    // graph (mode 1) -> L4f
    gemm_mf<<<dim3(16, 16, G), 256, 0, stream>>>(
        Gah, Gal, Glda, (long long)N_ * Glda, Gah, Gal, Glda, (long long)N_ * Glda,
        nullptr, 0, 0, p.L4f, nullptr, nullptr, N_, NN,
        N_, GK, N_, 1.f, 0.f, 1, p.sq, N_, 1);
    rowsum_dinv_kernel<<<(int)GN, 256, 0, stream>>>(p.L4f, p.dinv, N_);
    cvt_scaleL_kernel<<<4096, 256, 0, stream>>>(p.L4f, p.dinv, p.Lh, p.Ll, N_, G * NN);
    // chebyshev recurrence into Tcat slices
    for (int k = 1; k < taps; ++k) {
      float* Ck = p.Tcf + (long long)k * Fin;
      const float* Dp = nullptr; int Dld = 0; float beta = 0.f;
      if (k == 2) { Dp = X; Dld = Fin; beta = -1.f; }
      else if (k > 2) { Dp = p.Tcf + (long long)(k - 2) * Fin; Dld = Ktot; beta = -1.f; }
      initC_kernel<<<blk1d(GN * Fin), 256, 0, stream>>>(Ck, Ktot, Dp, Dld, GN, Fin, beta);
      int SK = (Fin <= 128) ? 4 : 1;
      gemm_mf<<<dim3((Fin + 127) / 128, 16, G * SK), 256, 0, stream>>>(
          p.Lh, p.Ll, N_, NN, p.TTh, p.TTl, N_, (long long)Fin * N_,
          nullptr, 0, 0, Ck, nullptr, nullptr, Ktot, (long long)N_ * Ktot,
          N_, N_, Fin, (k == 1) ? 1.f : 2.f, 0.f, 2, nullptr, 0, SK);
      cvt_rm_kernel<<<blk1d(GN * Fin), 256, 0, stream>>>(
          Ck, Ktot, p.Tch + (long long)k * Fin, p.Tcl + (long long)k * Fin, Kpad, GN, Fin);
      if (k + 1 < taps)
        cvt_tr_kernel<<<dim3((Fin + 31) / 32, 64, G), dim3(32, 8), 0, stream>>>(
            Ck, Ktot, (long long)N_ * Ktot, p.TTh, p.TTl, N_, (long long)Fin * N_, N_, Fin);
    }
    // merged projection: Hc = Tcat @ Wcat
    gemm_mf<<<dim3(Fout / 128, (int)(GN / 128), 1), 256, 0, stream>>>(
        p.Tch, p.Tcl, Kpad, 0, Wh, Wl, Kpad, 0,
        nullptr, 0, 0, Hc, nullptr, nullptr, Fout, 0,
        (int)GN, Kpad, Fout, 1.f, 0.f, 0, nullptr, 0, 1);
    bias_relu_kernel<<<4096, 256, 0, stream>>>(Hc, bias, GN * Fout, Fout);
    // HcT f32 + planes
    transpose_f32<<<dim3(Fout / 32, (int)(GN / 32)), dim3(32, 8), 0, stream>>>(Hc, p.HcTf, (int)GN, Fout);
    cvt_rm_kernel<<<blk1d((long long)Fout * GN), 256, 0, stream>>>(
        p.HcTf, (int)GN, p.HTh, p.HTl, (int)GN, Fout, (int)GN);
    // LHT = HcT @ L + HcT  (mode 3: write planes directly)
    gemm_mf<<<dim3(16, Fout / 128, G), 256, 0, stream>>>(
        p.HTh, p.HTl, (int)GN, (long long)N_, p.Lh, p.Ll, N_, NN,
        p.HcTf, (int)GN, (long long)N_, nullptr, p.LHh, p.LHl, (int)GN, (long long)N_,
        Fout, N_, N_, 1.f, 1.f, 3, nullptr, 0, 1);
    // Mm += HcT @ LHT^T (mode 2, split-K 8)
    gemm_mf<<<dim3(Fout / 128, Fout / 128, 8), 256, 0, stream>>>(
        p.HTh, p.HTl, (int)GN, 0, p.LHh, p.LHl, (int)GN, 0,
        nullptr, 0, 0, Mm, nullptr, nullptr, Fout, 0,
        Fout, (int)GN, Fout, 1.f, 0.f, 2, nullptr, 0, 8);
  };

  for (int c = 0; c < B_ / G; ++c) {
    const float* Xc = x + (long long)c * GN * 6;
    do_layer(Xc, 6, 6, 128, b1, p.W1h, p.W1l, 64, p.Hc1, p.Mm1);
    do_layer(p.Hc1, 128, 5, 512, b2, p.W2h, p.W2l, 640, p.Hc2, p.Mm2);
    do_layer(p.Hc2, 512, 3, 1024, b3, p.W3h, p.W3l, 1536, p.Hc3, p.Mm3);
    maxpool_kernel<<<(G * 1024 + 255) / 256, 256, 0, stream>>>(
        p.Hc3, p.gb + (long long)c * G * 1024, N_, 1024, G * 1024);
  }

  sumsq_kernel<<<64, 256, 0, stream>>>(p.Mm1, 128LL * 128, p.scal + 0);
  sumsq_kernel<<<256, 256, 0, stream>>>(p.Mm2, 512LL * 512, p.scal + 1);
  sumsq_kernel<<<256, 256, 0, stream>>>(p.Mm3, 1024LL * 1024, p.scal + 2);

  fc_kernel<<<(B_ * 512 * 64 + 255) / 256, 256, 0, stream>>>(p.gb, fw1, fb1, p.o1, B_, 1024, 512, 1);
  fc_kernel<<<(B_ * 128 * 64 + 255) / 256, 256, 0, stream>>>(p.o1, fw2, fb2, p.o2, B_, 512, 128, 1);
  fc_kernel<<<(B_ * 10 * 64 + 255) / 256, 256, 0, stream>>>(p.o2, fw3, fb3, out, B_, 128, 10, 0);

  sumsq_kernel<<<256, 256, 0, stream>>>(fw1, 512LL * 1024, p.scal + 3);
  sumsq_kernel<<<1, 256, 0, stream>>>(fb1, 512LL, p.scal + 4);
  finalize_kernel<<<1, 64, 0, stream>>>(p.scal, out + 160);
}

// Round 6
// 14982.251 us; speedup vs baseline: 2.0063x; 1.0209x over previous
//
#include <hip/hip_runtime.h>

#define B_ 16
#define N_ 2048

typedef __attribute__((ext_vector_type(8))) short s16x8;
typedef __attribute__((ext_vector_type(4))) float f32x4;

#define GLOAD16(gp, lp) __builtin_amdgcn_global_load_lds( \
    (const __attribute__((address_space(1))) void*)(gp),  \
    (__attribute__((address_space(3))) void*)(lp), 16, 0, 0)

__device__ inline unsigned short f2bf(float f) {
  unsigned u = __float_as_uint(f);
  u += 0x7FFFu + ((u >> 16) & 1u);
  return (unsigned short)(u >> 16);
}
__device__ inline float bf2f(unsigned short h) {
  return __uint_as_float(((unsigned)h) << 16);
}

// ---------------- small utility kernels ----------------

static __global__ void zerof_kernel(float* p, long long n) {
  long long i = (long long)blockIdx.x * blockDim.x + threadIdx.x;
  long long st = (long long)gridDim.x * blockDim.x;
  for (; i < n; i += st) p[i] = 0.f;
}

// sq[i] = sum_f X[i*F+f]^2 (thread per row; F small)
static __global__ void rowsq_small(const float* __restrict__ X, float* __restrict__ sq,
                                   int F, long long R) {
  long long i = (long long)blockIdx.x * blockDim.x + threadIdx.x;
  if (i >= R) return;
  const float* xr = X + i * F;
  float s = 0.f;
  for (int f = 0; f < F; ++f) s += xr[f] * xr[f];
  sq[i] = s;
}

// sq[g] = sum_f XT[f*GN+g]^2 (transposed input, coalesced)
static __global__ void colsq_kernel(const float* __restrict__ XT, float* __restrict__ sq,
                                    int F, long long GN) {
  long long g = (long long)blockIdx.x * blockDim.x + threadIdx.x;
  if (g >= GN) return;
  float s = 0.f;
  for (int f = 0; f < F; ++f) { float v = XT[(long long)f * GN + g]; s += v * v; }
  sq[g] = s;
}

static __global__ void rowsum_dinv_kernel(const float* __restrict__ A, float* __restrict__ dinv, int N) {
  long long row = blockIdx.x;
  const float* ar = A + row * N;
  float s = 0.f;
  for (int j = threadIdx.x; j < N; j += blockDim.x) s += ar[j];
  __shared__ float red[256];
  red[threadIdx.x] = s;
  __syncthreads();
  for (int st = 128; st > 0; st >>= 1) {
    if (threadIdx.x < st) red[threadIdx.x] += red[threadIdx.x + st];
    __syncthreads();
  }
  if (threadIdx.x == 0) {
    float d = red[0];
    dinv[row] = (d > 0.f) ? rsqrtf(d) : 0.f;
  }
}

// row-major convert to planes
static __global__ void cvt_rm_kernel(const float* __restrict__ src, int lds,
                                     short* __restrict__ dh, short* __restrict__ dl,
                                     int ldd, long long R, int Cc) {
  long long total = R * Cc;
  long long i = (long long)blockIdx.x * blockDim.x + threadIdx.x;
  long long st = (long long)gridDim.x * blockDim.x;
  for (; i < total; i += st) {
    long long r = i / Cc; int c = (int)(i - r * Cc);
    float v = src[r * lds + c];
    unsigned short h = f2bf(v);
    dh[r * ldd + c] = (short)h;
    dl[r * ldd + c] = (short)f2bf(v - bf2f(h));
  }
}

// transposed convert: dst[c][r] = src[r][c] (per z)
static __global__ void cvt_tr_kernel(const float* __restrict__ src, int lds, long long sS,
                                     short* __restrict__ dh, short* __restrict__ dl,
                                     int ldd, long long sD, int R, int Cc) {
  int z = blockIdx.z;
  src += (long long)z * sS;
  dh += (long long)z * sD;
  dl += (long long)z * sD;
  __shared__ float tile[32][33];
  int r0 = blockIdx.y * 32, c0 = blockIdx.x * 32;
  int tx = threadIdx.x, ty = threadIdx.y;
#pragma unroll
  for (int i = 0; i < 32; i += 8) {
    int r = r0 + ty + i, cx = c0 + tx;
    tile[ty + i][tx] = (r < R && cx < Cc) ? src[(long long)r * lds + cx] : 0.f;
  }
  __syncthreads();
#pragma unroll
  for (int i = 0; i < 32; i += 8) {
    int cr = c0 + ty + i, rx = r0 + tx;
    if (cr < Cc && rx < R) {
      float v = tile[tx][ty + i];
      unsigned short h = f2bf(v);
      dh[(long long)cr * ldd + rx] = (short)h;
      dl[(long long)cr * ldd + rx] = (short)f2bf(v - bf2f(h));
    }
  }
}

// dual convert: src (R x Cc, ld lds) f32 -> row-major planes (ld ldr) AND transposed planes (ld ldt)
static __global__ void cvt_dual_kernel(const float* __restrict__ src, int lds,
                                       short* __restrict__ rh, short* __restrict__ rl, int ldr,
                                       short* __restrict__ th, short* __restrict__ tl, long long ldt,
                                       int R, int Cc) {
  __shared__ float tile[32][33];
  int r0 = blockIdx.y * 32, c0 = blockIdx.x * 32;
  int tx = threadIdx.x, ty = threadIdx.y;
#pragma unroll
  for (int i = 0; i < 32; i += 8) {
    int r = r0 + ty + i, cx = c0 + tx;
    float v = (r < R && cx < Cc) ? src[(long long)r * lds + cx] : 0.f;
    tile[ty + i][tx] = v;
    if (r < R && cx < Cc) {
      unsigned short h = f2bf(v);
      rh[(long long)r * ldr + cx] = (short)h;
      rl[(long long)r * ldr + cx] = (short)f2bf(v - bf2f(h));
    }
  }
  __syncthreads();
#pragma unroll
  for (int i = 0; i < 32; i += 8) {
    int cr = c0 + ty + i, rx = r0 + tx;
    if (cr < Cc && rx < R) {
      float v = tile[tx][ty + i];
      unsigned short h = f2bf(v);
      th[(long long)cr * ldt + rx] = (short)h;
      tl[(long long)cr * ldt + rx] = (short)f2bf(v - bf2f(h));
    }
  }
}

// L planes = hi/lo of (-A[i]*dinv_r*dinv_j)
static __global__ void cvt_scaleL_kernel(const float* __restrict__ A, const float* __restrict__ dinv,
                                         short* __restrict__ dh, short* __restrict__ dl,
                                         int N, long long total) {
  long long i = (long long)blockIdx.x * blockDim.x + threadIdx.x;
  long long st = (long long)gridDim.x * blockDim.x;
  for (; i < total; i += st) {
    long long bn = i / N; int j = (int)(i - bn * N);
    long long b = bn / N; int r = (int)(bn - b * N);
    float v = -A[i] * dinv[b * N + r] * dinv[b * N + j];
    unsigned short h = f2bf(v);
    dh[i] = (short)h;
    dl[i] = (short)f2bf(v - bf2f(h));
  }
}

static __global__ void pad0_kernel(short* ph, short* pl, int ld, long long R, int c0, int c1) {
  int w = c1 - c0;
  long long total = R * w;
  long long i = (long long)blockIdx.x * blockDim.x + threadIdx.x;
  long long st = (long long)gridDim.x * blockDim.x;
  for (; i < total; i += st) {
    long long r = i / w; int c = c0 + (int)(i - r * w);
    ph[r * ld + c] = 0;
    pl[r * ld + c] = 0;
  }
}

static __global__ void initC_kernel(float* C, int ldc, const float* D, int ldd,
                                    long long R, int Cc, float beta) {
  long long total = R * Cc;
  long long i = (long long)blockIdx.x * blockDim.x + threadIdx.x;
  long long st = (long long)gridDim.x * blockDim.x;
  for (; i < total; i += st) {
    long long r = i / Cc; int c = (int)(i - r * Cc);
    C[r * ldc + c] = D ? beta * D[r * ldd + c] : 0.f;
  }
}

// initC from plane-pair D
static __global__ void initCp_kernel(float* C, int ldc, const short* __restrict__ Dh,
                                     const short* __restrict__ Dl, int ldd,
                                     long long R, int Cc, float beta) {
  long long total = R * Cc;
  long long i = (long long)blockIdx.x * blockDim.x + threadIdx.x;
  long long st = (long long)gridDim.x * blockDim.x;
  for (; i < total; i += st) {
    long long r = i / Cc; int c = (int)(i - r * Cc);
    float v = bf2f((unsigned short)Dh[r * ldd + c]) + bf2f((unsigned short)Dl[r * ldd + c]);
    C[r * ldc + c] = beta * v;
  }
}

// ---------------- MFMA split-bf16 GEMM (plane inputs, global_load_lds staging) ----------------
// acc = A(MxK) * BT(NcxK)^T over this split's k-range.  REQUIRES: M%128==0, K%32==0.
// mode 0: C = alpha*acc + beta*D
// mode 1: graph: C = (r==c) ? 0 : exp(-(sq_r+sq_c-2*acc))
// mode 2: atomicAdd(C, alpha*acc)
// mode 3: planes Ch/Cl = split(alpha*acc + beta*D)
// mode 4: o = relu(acc + bias[R]); C = o; planes Ch/Cl = split(o)
static __global__ __launch_bounds__(256) void gemm_mf(
    const short* __restrict__ Ah, const short* __restrict__ Al, int lda, long long sA,
    const short* __restrict__ Bh, const short* __restrict__ Bl, int ldb, long long sB,
    const float* D, int ldd, long long sD,
    float* C, short* Ch, short* Cl, int ldc, long long sC,
    int M, int K, int Nc,
    float alpha, float beta,
    int mode, const float* sqp, long long sSq, int ksplit,
    const float* __restrict__ bias) {
  int bz = blockIdx.z;
  int zb = bz / ksplit, zk = bz - zb * ksplit;
  Ah += (long long)zb * sA; Al += (long long)zb * sA;
  Bh += (long long)zb * sB; Bl += (long long)zb * sB;
  if (C) C += (long long)zb * sC;
  if (Ch) { Ch += (long long)zb * sC; Cl += (long long)zb * sC; }
  if (D) D += (long long)zb * sD;
  const float* sqb = sqp ? sqp + (long long)zb * sSq : nullptr;

  int k_begin = 0, k_end = K;
  if (ksplit > 1) {
    int kslice = (((K / ksplit) + 31) >> 5) << 5;
    k_begin = zk * kslice;
    k_end = min(K, k_begin + kslice);
  }

  // [plane][kb][row][8]: plane 0=aH 1=aL 2=bH 3=bL; linear offset = idx*8, idx=kb*128+row
  __shared__ __align__(16) short smem[4][4][128][8];

  int row0 = blockIdx.y * 128, col0 = blockIdx.x * 128;
  int t = threadIdx.x;
  int w = t >> 6, lane = t & 63, g = lane >> 4, c = lane & 15;
  int wr = w >> 1, wc = w & 1;

  // this wave's staging plane
  const short* gp = (w == 0) ? Ah : (w == 1) ? Al : (w == 2) ? Bh : Bl;
  long long gld = (w < 2) ? lda : ldb;
  long long grow0 = (w < 2) ? row0 : col0;
  short* lbase = &smem[w][0][0][0];

  f32x4 acc[4][4];
#pragma unroll
  for (int i = 0; i < 4; ++i)
#pragma unroll
    for (int j = 0; j < 4; ++j) {
      acc[i][j][0] = 0.f; acc[i][j][1] = 0.f; acc[i][j][2] = 0.f; acc[i][j][3] = 0.f;
    }

  for (int k0 = k_begin; k0 < k_end; k0 += 32) {
#pragma unroll
    for (int q = 0; q < 8; ++q) {
      int idx = q * 64 + lane;
      int row = idx & 127;
      int kb = idx >> 7;
      const short* src = gp + (grow0 + row) * gld + k0 + kb * 8;
      GLOAD16(src, lbase + idx * 8);
    }
    __syncthreads();
    s16x8 afH[4], afL[4], bfH[4], bfL[4];
#pragma unroll
    for (int mi = 0; mi < 4; ++mi) {
      int row = wr * 64 + mi * 16 + c;
      afH[mi] = *reinterpret_cast<const s16x8*>(&smem[0][g][row][0]);
      afL[mi] = *reinterpret_cast<const s16x8*>(&smem[1][g][row][0]);
    }
#pragma unroll
    for (int ni = 0; ni < 4; ++ni) {
      int row = wc * 64 + ni * 16 + c;
      bfH[ni] = *reinterpret_cast<const s16x8*>(&smem[2][g][row][0]);
      bfL[ni] = *reinterpret_cast<const s16x8*>(&smem[3][g][row][0]);
    }
#pragma unroll
    for (int mi = 0; mi < 4; ++mi)
#pragma unroll
      for (int ni = 0; ni < 4; ++ni) {
        acc[mi][ni] = __builtin_amdgcn_mfma_f32_16x16x32_bf16(afH[mi], bfH[ni], acc[mi][ni], 0, 0, 0);
        acc[mi][ni] = __builtin_amdgcn_mfma_f32_16x16x32_bf16(afH[mi], bfL[ni], acc[mi][ni], 0, 0, 0);
        acc[mi][ni] = __builtin_amdgcn_mfma_f32_16x16x32_bf16(afL[mi], bfH[ni], acc[mi][ni], 0, 0, 0);
      }
    __syncthreads();
  }

#pragma unroll
  for (int mi = 0; mi < 4; ++mi) {
#pragma unroll
    for (int ni = 0; ni < 4; ++ni) {
#pragma unroll
      for (int r = 0; r < 4; ++r) {
        int R = row0 + wr * 64 + mi * 16 + g * 4 + r;
        int Cc2 = col0 + wc * 64 + ni * 16 + c;
        if (R < M && Cc2 < Nc) {
          float v = acc[mi][ni][r];
          long long idx = (long long)R * ldc + Cc2;
          if (mode == 1) {
            float d2 = sqb[R] + sqb[Cc2] - 2.f * v;
            C[idx] = (R == Cc2) ? 0.f : expf(-d2);
          } else if (mode == 2) {
            atomicAdd(&C[idx], alpha * v);
          } else if (mode == 4) {
            float o = fmaxf(v + bias[R], 0.f);
            C[idx] = o;
            unsigned short h = f2bf(o);
            Ch[idx] = (short)h;
            Cl[idx] = (short)f2bf(o - bf2f(h));
          } else {
            float o = alpha * v;
            if (D) o += beta * D[(long long)R * ldd + Cc2];
            if (mode == 3) {
              unsigned short h = f2bf(o);
              Ch[idx] = (short)h;
              Cl[idx] = (short)f2bf(o - bf2f(h));
            } else {
              C[idx] = o;
            }
          }
        }
      }
    }
  }
}

// ---------------- reductions / pool / FC ----------------

static __global__ void sumsq_kernel(const float* __restrict__ src, long long n, float* out) {
  float s = 0.f;
  long long i = (long long)blockIdx.x * blockDim.x + threadIdx.x;
  long long st = (long long)gridDim.x * blockDim.x;
  for (; i < n; i += st) { float v = src[i]; s += v * v; }
  __shared__ float red[256];
  red[threadIdx.x] = s;
  __syncthreads();
  for (int stp = 128; stp > 0; stp >>= 1) {
    if (threadIdx.x < stp) red[threadIdx.x] += red[threadIdx.x + stp];
    __syncthreads();
  }
  if (threadIdx.x == 0) atomicAdd(out, red[0]);
}

// g[b*F+f] = max_n HT[f*GNcols + b*N + n]  (wave per (b,f), coalesced rows)
static __global__ void maxpool_rows_kernel(const float* __restrict__ HT, float* __restrict__ g,
                                           int N, long long GNcols, int F, int Gb) {
  int wid = (int)(((long long)blockIdx.x * blockDim.x + threadIdx.x) >> 6);
  int lane = threadIdx.x & 63;
  if (wid >= Gb * F) return;
  int b = wid / F, f = wid - b * F;
  const float* src = HT + (long long)f * GNcols + (long long)b * N;
  float m = -INFINITY;
  for (int n = lane; n < N; n += 64) m = fmaxf(m, src[n]);
  for (int off = 32; off; off >>= 1) m = fmaxf(m, __shfl_down(m, off));
  if (lane == 0) g[(long long)b * F + f] = m;
}

static __global__ void fc_kernel(const float* __restrict__ in, const float* __restrict__ W,
                                 const float* __restrict__ bias, float* out,
                                 int Bc, int K, int J, int do_relu) {
  int gtid = blockIdx.x * blockDim.x + threadIdx.x;
  int wid = gtid >> 6;
  int lane = gtid & 63;
  if (wid >= Bc * J) return;
  int b = wid / J, j = wid - b * J;
  const float* ib = in + (long long)b * K;
  const float* wj = W + (long long)j * K;
  float s = 0.f;
  for (int k = lane; k < K; k += 64) s += ib[k] * wj[k];
  for (int off = 32; off > 0; off >>= 1) s += __shfl_down(s, off);
  if (lane == 0) {
    s += bias[j];
    out[wid] = do_relu ? fmaxf(s, 0.f) : s;
  }
}

static __global__ void finalize_kernel(const float* scal, float* out_regs) {
  if (threadIdx.x == 0 && blockIdx.x == 0) {
    float r1 = sqrtf(scal[0]), r2 = sqrtf(scal[1]), r3 = sqrtf(scal[2]);
    float nw = sqrtf(scal[3]), nb = sqrtf(scal[4]);
    out_regs[0] = r1; out_regs[1] = r2; out_regs[2] = r3;
    out_regs[3] = nw; out_regs[4] = nb;
    out_regs[5] = nw; out_regs[6] = nb;
    out_regs[7] = nw; out_regs[8] = nb;
  }
}

// ---------------- host orchestration ----------------

struct Ptrs {
  float *L4f, *Tcf, *HcTfA, *HcTfB;
  float *Mm1, *Mm2, *Mm3, *sq, *dinv, *gb, *o1, *o2, *scal;
  short *Lh, *Ll, *Tch, *Tcl, *TTh, *TTl, *Xgh, *Xgl, *HTh, *HTl, *LHh, *LHl;
  short *W1h, *W1l, *W2h, *W2l, *W3h, *W3l;
};

extern "C" void kernel_launch(void* const* d_in, const int* in_sizes, int n_in,
                              void* d_out, int out_size, void* d_ws, size_t ws_size,
                              hipStream_t stream) {
  const float* x   = (const float*)d_in[0];
  const float* w1  = (const float*)d_in[4];
  const float* b1  = (const float*)d_in[5];
  const float* w2  = (const float*)d_in[6];
  const float* b2  = (const float*)d_in[7];
  const float* w3  = (const float*)d_in[8];
  const float* b3  = (const float*)d_in[9];
  const float* fw1 = (const float*)d_in[10];
  const float* fb1 = (const float*)d_in[11];
  const float* fw2 = (const float*)d_in[12];
  const float* fb2 = (const float*)d_in[13];
  const float* fw3 = (const float*)d_in[14];
  const float* fb3 = (const float*)d_in[15];
  float* out = (float*)d_out;

  float* ws = (float*)d_ws;
  const long long NN = (long long)N_ * N_;

  Ptrs p;
  auto layout = [&](int G) -> unsigned long long {
    long long off = 0;
    auto aF = [&](long long n) { float* q = ws + off; off += (n + 7) & ~7LL; return q; };
    auto aS = [&](long long n) { short* q = (short*)(ws + off); off += (((n + 1) >> 1) + 7) & ~7LL; return q; };
    long long GN = (long long)G * N_;
    p.L4f = aF(G * NN);
    p.Lh = aS(G * NN); p.Ll = aS(G * NN);
    p.Tcf = aF(GN * 1536);
    p.Tch = aS(GN * 1536); p.Tcl = aS(GN * 1536);
    p.TTh = aS(GN * 512); p.TTl = aS(GN * 512);
    p.Xgh = aS(GN * 32); p.Xgl = aS(GN * 32);
    p.HcTfA = aF(GN * 1024); p.HcTfB = aF(GN * 1024);
    p.HTh = aS(GN * 1024); p.HTl = aS(GN * 1024);
    p.LHh = aS(GN * 1024); p.LHl = aS(GN * 1024);
    p.W1h = aS(128 * 64); p.W1l = aS(128 * 64);
    p.W2h = aS(512 * 640); p.W2l = aS(512 * 640);
    p.W3h = aS(1024 * 1536); p.W3l = aS(1024 * 1536);
    p.Mm1 = aF(128 * 128); p.Mm2 = aF(512 * 512); p.Mm3 = aF(1024 * 1024);
    p.sq = aF(GN); p.dinv = aF(GN);
    p.gb = aF(B_ * 1024); p.o1 = aF(B_ * 512); p.o2 = aF(B_ * 128);
    p.scal = aF(16);
    return (unsigned long long)off * 4ULL;
  };
  int G = 4;
  while (G > 1 && layout(G) > ws_size) G >>= 1;
  if (layout(G) > ws_size) return;
  layout(G);

  const long long GN = (long long)G * N_;
  auto blk1d = [](long long n) { return (int)(((n + 255) / 256 < 4096) ? (n + 255) / 256 : 4096); };

  // ---- W plane conversions: Wcat^T layout (Fout x Kpad), taps at col k*Fin ----
  cvt_tr_kernel<<<dim3(4, 1, 6), dim3(32, 8), 0, stream>>>(
      w1, 128, 6LL * 128, p.W1h, p.W1l, 64, 6, 6, 128);
  pad0_kernel<<<blk1d(128LL * 28), 256, 0, stream>>>(p.W1h, p.W1l, 64, 128, 36, 64);
  cvt_tr_kernel<<<dim3(16, 4, 5), dim3(32, 8), 0, stream>>>(
      w2, 512, 128LL * 512, p.W2h, p.W2l, 640, 128, 128, 512);
  cvt_tr_kernel<<<dim3(32, 16, 3), dim3(32, 8), 0, stream>>>(
      w3, 1024, 512LL * 1024, p.W3h, p.W3l, 1536, 512, 512, 1024);
  pad0_kernel<<<blk1d(GN * 26), 256, 0, stream>>>(p.Xgh, p.Xgl, 32, GN, 6, 32);

  zerof_kernel<<<1, 256, 0, stream>>>(p.scal, 16);
  zerof_kernel<<<64, 256, 0, stream>>>(p.Mm1, 128LL * 128);
  zerof_kernel<<<256, 256, 0, stream>>>(p.Mm2, 512LL * 512);
  zerof_kernel<<<1024, 256, 0, stream>>>(p.Mm3, 1024LL * 1024);

  // Xrm: row-major f32 input (layer 1) or null; XT: transposed f32 input (layers 2/3)
  auto do_layer = [&](const float* Xrm, const float* XT, int Fin, int taps, int Fout,
                      const float* bias, const short* Wh, const short* Wl, int Kpad,
                      float* HcTf, int recSK, int mmSK, float* Mm) {
    int Ktot = taps * Fin;
    if (Xrm) {
      rowsq_small<<<blk1d(GN), 256, 0, stream>>>(Xrm, p.sq, Fin, GN);
      cvt_rm_kernel<<<blk1d(GN * Fin), 256, 0, stream>>>(Xrm, Fin, p.Tch, p.Tcl, Kpad, GN, Fin);
      pad0_kernel<<<blk1d(GN * (Kpad - Ktot)), 256, 0, stream>>>(p.Tch, p.Tcl, Kpad, GN, Ktot, Kpad);
      cvt_rm_kernel<<<blk1d(GN * Fin), 256, 0, stream>>>(Xrm, Fin, p.Xgh, p.Xgl, 32, GN, Fin);
      cvt_tr_kernel<<<dim3(1, 64, G), dim3(32, 8), 0, stream>>>(
          Xrm, Fin, (long long)N_ * Fin, p.TTh, p.TTl, (int)GN, N_, N_, Fin);
    } else {
      colsq_kernel<<<blk1d(GN), 256, 0, stream>>>(XT, p.sq, Fin, GN);
      cvt_tr_kernel<<<dim3((int)(GN / 32), Fin / 32, 1), dim3(32, 8), 0, stream>>>(
          XT, (int)GN, 0, p.Tch, p.Tcl, Kpad, 0, Fin, (int)GN);
      cvt_rm_kernel<<<blk1d((long long)Fin * GN), 256, 0, stream>>>(
          XT, (int)GN, p.TTh, p.TTl, (int)GN, Fin, (int)GN);
    }
    // graph (mode 1) -> L4f
    const short* Gah = Xrm ? p.Xgh : p.Tch;
    const short* Gal = Xrm ? p.Xgl : p.Tcl;
    int Glda = Xrm ? 32 : Kpad;
    int GK = Xrm ? 32 : Fin;
    gemm_mf<<<dim3(16, 16, G), 256, 0, stream>>>(
        Gah, Gal, Glda, (long long)N_ * Glda, Gah, Gal, Glda, (long long)N_ * Glda,
        nullptr, 0, 0, p.L4f, nullptr, nullptr, N_, NN,
        N_, GK, N_, 1.f, 0.f, 1, p.sq, N_, 1, nullptr);
    rowsum_dinv_kernel<<<(int)GN, 256, 0, stream>>>(p.L4f, p.dinv, N_);
    cvt_scaleL_kernel<<<4096, 256, 0, stream>>>(p.L4f, p.dinv, p.Lh, p.Ll, N_, G * NN);
    // chebyshev recurrence
    for (int k = 1; k < taps; ++k) {
      float* Ck = p.Tcf + (long long)k * Fin;
      if (k == 1) {
        initC_kernel<<<blk1d(GN * Fin), 256, 0, stream>>>(Ck, Ktot, nullptr, 0, GN, Fin, 0.f);
      } else if (k == 2) {
        if (Xrm) initC_kernel<<<blk1d(GN * Fin), 256, 0, stream>>>(Ck, Ktot, Xrm, Fin, GN, Fin, -1.f);
        else initCp_kernel<<<blk1d(GN * Fin), 256, 0, stream>>>(Ck, Ktot, p.Tch, p.Tcl, Kpad, GN, Fin, -1.f);
      } else {
        initC_kernel<<<blk1d(GN * Fin), 256, 0, stream>>>(
            Ck, Ktot, p.Tcf + (long long)(k - 2) * Fin, Ktot, GN, Fin, -1.f);
      }
      gemm_mf<<<dim3((Fin + 127) / 128, 16, G * recSK), 256, 0, stream>>>(
          p.Lh, p.Ll, N_, NN, p.TTh, p.TTl, (int)GN, N_,
          nullptr, 0, 0, Ck, nullptr, nullptr, Ktot, (long long)N_ * Ktot,
          N_, N_, Fin, (k == 1) ? 1.f : 2.f, 0.f, 2, nullptr, 0, recSK, nullptr);
      cvt_dual_kernel<<<dim3((Fin + 31) / 32, (int)(GN / 32)), dim3(32, 8), 0, stream>>>(
          Ck, Ktot, p.Tch + (long long)k * Fin, p.Tcl + (long long)k * Fin, Kpad,
          p.TTh, p.TTl, GN, (int)GN, Fin);
    }
    // projection (mode 4): HcT = Wcat^T @ Tcat^T, fused bias+relu, writes f32 + HT planes
    gemm_mf<<<dim3((int)(GN / 128), Fout / 128, 1), 256, 0, stream>>>(
        Wh, Wl, Kpad, 0, p.Tch, p.Tcl, Kpad, 0, nullptr, 0, 0,
        HcTf, p.HTh, p.HTl, (int)GN, 0, Fout, Kpad, (int)GN, 1.f, 0.f, 4, nullptr, 0, 1, bias);
    // LHT = H^T L + H^T (mode 3: planes out)
    gemm_mf<<<dim3(16, Fout / 128, G), 256, 0, stream>>>(
        p.HTh, p.HTl, (int)GN, N_, p.Lh, p.Ll, N_, NN,
        HcTf, (int)GN, N_, nullptr, p.LHh, p.LHl, (int)GN, N_,
        Fout, N_, N_, 1.f, 1.f, 3, nullptr, 0, 1, nullptr);
    // Mm += H^T (L+I) H (mode 2, split-K)
    gemm_mf<<<dim3(Fout / 128, Fout / 128, mmSK), 256, 0, stream>>>(
        p.HTh, p.HTl, (int)GN, 0, p.LHh, p.LHl, (int)GN, 0,
        nullptr, 0, 0, Mm, nullptr, nullptr, Fout, 0,
        Fout, (int)GN, Fout, 1.f, 0.f, 2, nullptr, 0, mmSK, nullptr);
  };

  for (int c = 0; c < B_ / G; ++c) {
    const float* Xc = x + (long long)c * GN * 6;
    do_layer(Xc, nullptr,   6,   6, 128,  b1, p.W1h, p.W1l, 64,   p.HcTfA, 8, 64, p.Mm1);
    do_layer(nullptr, p.HcTfA, 128, 5, 512,  b2, p.W2h, p.W2l, 640,  p.HcTfB, 8, 32, p.Mm2);
    do_layer(nullptr, p.HcTfB, 512, 3, 1024, b3, p.W3h, p.W3l, 1536, p.HcTfA, 2, 8,  p.Mm3);
    maxpool_rows_kernel<<<(G * 1024 * 64 + 255) / 256, 256, 0, stream>>>(
        p.HcTfA, p.gb + (long long)c * G * 1024, N_, GN, 1024, G);
  }

  sumsq_kernel<<<64, 256, 0, stream>>>(p.Mm1, 128LL * 128, p.scal + 0);
  sumsq_kernel<<<256, 256, 0, stream>>>(p.Mm2, 512LL * 512, p.scal + 1);
  sumsq_kernel<<<256, 256, 0, stream>>>(p.Mm3, 1024LL * 1024, p.scal + 2);

  fc_kernel<<<(B_ * 512 * 64 + 255) / 256, 256, 0, stream>>>(p.gb, fw1, fb1, p.o1, B_, 1024, 512, 1);
  fc_kernel<<<(B_ * 128 * 64 + 255) / 256, 256, 0, stream>>>(p.o1, fw2, fb2, p.o2, B_, 512, 128, 1);
  fc_kernel<<<(B_ * 10 * 64 + 255) / 256, 256, 0, stream>>>(p.o2, fw3, fb3, out, B_, 128, 10, 0);

  sumsq_kernel<<<256, 256, 0, stream>>>(fw1, 512LL * 1024, p.scal + 3);
  sumsq_kernel<<<1, 256, 0, stream>>>(fb1, 512LL, p.scal + 4);
  finalize_kernel<<<1, 64, 0, stream>>>(p.scal, out + 160);
}

// Round 7
// 11159.214 us; speedup vs baseline: 2.6936x; 1.3426x over previous
//
#include <hip/hip_runtime.h>

#define B_ 16
#define N_ 2048

typedef __attribute__((ext_vector_type(8))) short s16x8;
typedef __attribute__((ext_vector_type(4))) float f32x4;

#define GLOAD16(gp, lp) __builtin_amdgcn_global_load_lds( \
    (const __attribute__((address_space(1))) void*)(gp),  \
    (__attribute__((address_space(3))) void*)(lp), 16, 0, 0)

__device__ inline unsigned short f2bf(float f) {
  unsigned u = __float_as_uint(f);
  u += 0x7FFFu + ((u >> 16) & 1u);
  return (unsigned short)(u >> 16);
}
__device__ inline float bf2f(unsigned short h) {
  return __uint_as_float(((unsigned)h) << 16);
}
__device__ inline float pget(const short* __restrict__ ph, const short* __restrict__ pl, long long i) {
  return bf2f((unsigned short)ph[i]) + bf2f((unsigned short)pl[i]);
}
__device__ inline void pput(short* __restrict__ ph, short* __restrict__ pl, long long i, float v) {
  unsigned short h = f2bf(v);
  ph[i] = (short)h;
  pl[i] = (short)f2bf(v - bf2f(h));
}

// ---------------- utility kernels ----------------

static __global__ void zerof_kernel(float* p, long long n) {
  long long i = (long long)blockIdx.x * blockDim.x + threadIdx.x;
  long long st = (long long)gridDim.x * blockDim.x;
  for (; i < n; i += st) p[i] = 0.f;
}

// sq[i] = sum_f X[i*F+f]^2 (f32 input, small F)
static __global__ void rowsq_small(const float* __restrict__ X, float* __restrict__ sq,
                                   int F, long long R) {
  long long i = (long long)blockIdx.x * blockDim.x + threadIdx.x;
  if (i >= R) return;
  const float* xr = X + i * F;
  float s = 0.f;
  for (int f = 0; f < F; ++f) s += xr[f] * xr[f];
  sq[i] = s;
}

// sq[g] = sum_f H[f*GN+g]^2 (plane input, coalesced)
static __global__ void colsq_p(const short* __restrict__ Hh, const short* __restrict__ Hl,
                               float* __restrict__ sq, int F, long long GN) {
  long long g = (long long)blockIdx.x * blockDim.x + threadIdx.x;
  if (g >= GN) return;
  float s = 0.f;
  for (int f = 0; f < F; ++f) { float v = pget(Hh, Hl, (long long)f * GN + g); s += v * v; }
  sq[g] = s;
}

// dinv[row] from plane adjacency row sums
static __global__ void rowsum_dinv_p(const short* __restrict__ Lh, const short* __restrict__ Ll,
                                     float* __restrict__ dinv, int N) {
  long long row = blockIdx.x;
  const short* hr = Lh + row * N;
  const short* lr = Ll + row * N;
  float s = 0.f;
  for (int j = threadIdx.x; j < N; j += blockDim.x)
    s += bf2f((unsigned short)hr[j]) + bf2f((unsigned short)lr[j]);
  __shared__ float red[256];
  red[threadIdx.x] = s;
  __syncthreads();
  for (int st = 128; st > 0; st >>= 1) {
    if (threadIdx.x < st) red[threadIdx.x] += red[threadIdx.x + st];
    __syncthreads();
  }
  if (threadIdx.x == 0) {
    float d = red[0];
    dinv[row] = (d > 0.f) ? rsqrtf(d) : 0.f;
  }
}

// in-place: L <- -L * dinv_r * dinv_j  (planes), N_=2048 hardcoded shifts
static __global__ void scaleL_p(short* Lh, short* Ll, const float* __restrict__ dinv, long long total) {
  long long i = (long long)blockIdx.x * blockDim.x + threadIdx.x;
  long long st = (long long)gridDim.x * blockDim.x;
  for (; i < total; i += st) {
    int j = (int)(i & (N_ - 1));
    long long bn = i >> 11;
    int r = (int)(bn & (N_ - 1));
    long long b = bn >> 11;
    float v = pget(Lh, Ll, i);
    v = -v * dinv[b * N_ + r] * dinv[b * N_ + j];
    pput(Lh, Ll, i, v);
  }
}

// f32 row-major -> planes
static __global__ void cvt_rm_kernel(const float* __restrict__ src, int lds,
                                     short* __restrict__ dh, short* __restrict__ dl,
                                     int ldd, long long R, int Cc) {
  long long total = R * Cc;
  long long i = (long long)blockIdx.x * blockDim.x + threadIdx.x;
  long long st = (long long)gridDim.x * blockDim.x;
  for (; i < total; i += st) {
    long long r = i / Cc; int c = (int)(i - r * Cc);
    pput(dh, dl, r * ldd + c, src[r * lds + c]);
  }
}

// f32 -> transposed planes (z-batched): dst[c][r] = src[r][c]
static __global__ void cvt_tr_kernel(const float* __restrict__ src, int lds, long long sS,
                                     short* __restrict__ dh, short* __restrict__ dl,
                                     long long ldd, long long sD, int R, int Cc) {
  int z = blockIdx.z;
  src += (long long)z * sS;
  dh += (long long)z * sD;
  dl += (long long)z * sD;
  __shared__ float tile[32][33];
  int r0 = blockIdx.y * 32, c0 = blockIdx.x * 32;
  int tx = threadIdx.x, ty = threadIdx.y;
#pragma unroll
  for (int i = 0; i < 32; i += 8) {
    int r = r0 + ty + i, cx = c0 + tx;
    tile[ty + i][tx] = (r < R && cx < Cc) ? src[(long long)r * lds + cx] : 0.f;
  }
  __syncthreads();
#pragma unroll
  for (int i = 0; i < 32; i += 8) {
    int cr = c0 + ty + i, rx = r0 + tx;
    if (cr < Cc && rx < R) pput(dh, dl, (long long)cr * ldd + rx, tile[tx][ty + i]);
  }
}

// plane->plane transpose: dst[c*ldd+r] = src[r*lds+c]  (both planes)
static __global__ void tr_pp_kernel(const short* __restrict__ sh, const short* __restrict__ sl,
                                    long long lds, short* __restrict__ dh, short* __restrict__ dl,
                                    int ldd, int R, long long Cc) {
  __shared__ short th[32][33], tl[32][33];
  int r0 = blockIdx.y * 32;
  long long c0 = (long long)blockIdx.x * 32;
  int tx = threadIdx.x, ty = threadIdx.y;
#pragma unroll
  for (int i = 0; i < 32; i += 8) {
    int r = r0 + ty + i;
    long long cx = c0 + tx;
    short vh = 0, vl = 0;
    if (r < R && cx < Cc) { vh = sh[(long long)r * lds + cx]; vl = sl[(long long)r * lds + cx]; }
    th[ty + i][tx] = vh;
    tl[ty + i][tx] = vl;
  }
  __syncthreads();
#pragma unroll
  for (int i = 0; i < 32; i += 8) {
    long long cr = c0 + ty + i;
    int rx = r0 + tx;
    if (cr < Cc && rx < R) {
      dh[cr * ldd + rx] = th[tx][ty + i];
      dl[cr * ldd + rx] = tl[tx][ty + i];
    }
  }
}

// f32 src -> row-major planes AND transposed planes
static __global__ void cvt_dual_kernel(const float* __restrict__ src, int lds,
                                       short* __restrict__ rh, short* __restrict__ rl, int ldr,
                                       short* __restrict__ th, short* __restrict__ tl, long long ldt,
                                       int R, int Cc) {
  __shared__ float tile[32][33];
  int r0 = blockIdx.y * 32, c0 = blockIdx.x * 32;
  int tx = threadIdx.x, ty = threadIdx.y;
#pragma unroll
  for (int i = 0; i < 32; i += 8) {
    int r = r0 + ty + i, cx = c0 + tx;
    float v = (r < R && cx < Cc) ? src[(long long)r * lds + cx] : 0.f;
    tile[ty + i][tx] = v;
    if (r < R && cx < Cc) pput(rh, rl, (long long)r * ldr + cx, v);
  }
  __syncthreads();
#pragma unroll
  for (int i = 0; i < 32; i += 8) {
    int cr = c0 + ty + i, rx = r0 + tx;
    if (cr < Cc && rx < R) pput(th, tl, (long long)cr * ldt + rx, tile[tx][ty + i]);
  }
}

static __global__ void pad0_kernel(short* ph, short* pl, int ld, long long R, int c0, int c1) {
  int w = c1 - c0;
  long long total = R * w;
  long long i = (long long)blockIdx.x * blockDim.x + threadIdx.x;
  long long st = (long long)gridDim.x * blockDim.x;
  for (; i < total; i += st) {
    long long r = i / w; int c = c0 + (int)(i - r * w);
    ph[r * ld + c] = 0;
    pl[r * ld + c] = 0;
  }
}

// Trec init: C = beta*D (f32 D) or 0
static __global__ void initC_kernel(float* C, int ldc, const float* D, int ldd,
                                    long long R, int Cc, float beta) {
  long long total = R * Cc;
  long long i = (long long)blockIdx.x * blockDim.x + threadIdx.x;
  long long st = (long long)gridDim.x * blockDim.x;
  for (; i < total; i += st) {
    long long r = i / Cc; int c = (int)(i - r * Cc);
    C[r * ldc + c] = D ? beta * D[r * ldd + c] : 0.f;
  }
}

// Trec init from plane D
static __global__ void initCp_kernel(float* C, int ldc, const short* __restrict__ Dh,
                                     const short* __restrict__ Dl, int ldd,
                                     long long R, int Cc, float beta) {
  long long total = R * Cc;
  long long i = (long long)blockIdx.x * blockDim.x + threadIdx.x;
  long long st = (long long)gridDim.x * blockDim.x;
  for (; i < total; i += st) {
    long long r = i / Cc; int c = (int)(i - r * Cc);
    C[r * ldc + c] = beta * pget(Dh, Dl, r * ldd + c);
  }
}

// ---------------- MFMA split-bf16 GEMM ----------------
// acc = A(MxK) @ BT(NcxK)^T over this split's k-range.  M%128==0, Nc%128==0, K%32==0.
// mode 2: atomicAdd(C, alpha*acc)
// mode 3: planes out: o = alpha*acc + beta*planeD
// mode 4: planes out: o = relu(acc + bias[R])
// mode 5: planes out: o = (R==Cc2)?0:exp(-(sq_r+sq_c-2*acc))
static __global__ __launch_bounds__(256) void gemm_mf(
    const short* __restrict__ Ah, const short* __restrict__ Al, int lda, long long sA,
    const short* __restrict__ Bh, const short* __restrict__ Bl, int ldb, long long sB,
    const short* Dh, const short* Dl, int ldd, long long sD,
    float* C, short* Ch, short* Cl, int ldc, long long sC,
    int M, int K, int Nc,
    float alpha, float beta,
    int mode, const float* sqp, long long sSq, int ksplit,
    const float* __restrict__ bias) {
  int bz = blockIdx.z;
  int zb = bz / ksplit, zk = bz - zb * ksplit;
  Ah += (long long)zb * sA; Al += (long long)zb * sA;
  Bh += (long long)zb * sB; Bl += (long long)zb * sB;
  if (C) C += (long long)zb * sC;
  if (Ch) { Ch += (long long)zb * sC; Cl += (long long)zb * sC; }
  if (Dh) { Dh += (long long)zb * sD; Dl += (long long)zb * sD; }
  const float* sqb = sqp ? sqp + (long long)zb * sSq : nullptr;

  int k_begin = 0, k_end = K;
  if (ksplit > 1) {
    int kslice = (((K / ksplit) + 31) >> 5) << 5;
    k_begin = zk * kslice;
    k_end = min(K, k_begin + kslice);
  }

  __shared__ __align__(16) short smem[4][4][128][8];  // 32 KB

  int row0 = blockIdx.y * 128, col0 = blockIdx.x * 128;
  int t = threadIdx.x;
  int w = t >> 6, lane = t & 63, g = lane >> 4, c = lane & 15;
  int wr = w >> 1, wc = w & 1;

  const short* gp = (w == 0) ? Ah : (w == 1) ? Al : (w == 2) ? Bh : Bl;
  long long gld = (w < 2) ? lda : ldb;
  long long grow0 = (w < 2) ? row0 : col0;
  short* lbase = &smem[w][0][0][0];

  f32x4 acc[4][4];
#pragma unroll
  for (int i = 0; i < 4; ++i)
#pragma unroll
    for (int j = 0; j < 4; ++j) {
      acc[i][j][0] = 0.f; acc[i][j][1] = 0.f; acc[i][j][2] = 0.f; acc[i][j][3] = 0.f;
    }

  for (int k0 = k_begin; k0 < k_end; k0 += 32) {
#pragma unroll
    for (int q = 0; q < 8; ++q) {
      int idx = q * 64 + lane;
      const short* src = gp + (grow0 + (idx & 127)) * gld + k0 + (idx >> 7) * 8;
      GLOAD16(src, lbase + idx * 8);
    }
    __syncthreads();
    s16x8 afH[4], afL[4], bfH[4], bfL[4];
#pragma unroll
    for (int mi = 0; mi < 4; ++mi) {
      int row = wr * 64 + mi * 16 + c;
      afH[mi] = *reinterpret_cast<const s16x8*>(&smem[0][g][row][0]);
      afL[mi] = *reinterpret_cast<const s16x8*>(&smem[1][g][row][0]);
    }
#pragma unroll
    for (int ni = 0; ni < 4; ++ni) {
      int row = wc * 64 + ni * 16 + c;
      bfH[ni] = *reinterpret_cast<const s16x8*>(&smem[2][g][row][0]);
      bfL[ni] = *reinterpret_cast<const s16x8*>(&smem[3][g][row][0]);
    }
#pragma unroll
    for (int mi = 0; mi < 4; ++mi)
#pragma unroll
      for (int ni = 0; ni < 4; ++ni) {
        acc[mi][ni] = __builtin_amdgcn_mfma_f32_16x16x32_bf16(afH[mi], bfH[ni], acc[mi][ni], 0, 0, 0);
        acc[mi][ni] = __builtin_amdgcn_mfma_f32_16x16x32_bf16(afH[mi], bfL[ni], acc[mi][ni], 0, 0, 0);
        acc[mi][ni] = __builtin_amdgcn_mfma_f32_16x16x32_bf16(afL[mi], bfH[ni], acc[mi][ni], 0, 0, 0);
      }
    __syncthreads();
  }

#pragma unroll
  for (int mi = 0; mi < 4; ++mi) {
#pragma unroll
    for (int ni = 0; ni < 4; ++ni) {
#pragma unroll
      for (int r = 0; r < 4; ++r) {
        int R = row0 + wr * 64 + mi * 16 + g * 4 + r;
        int Cc2 = col0 + wc * 64 + ni * 16 + c;
        if (R < M && Cc2 < Nc) {
          float v = acc[mi][ni][r];
          long long idx = (long long)R * ldc + Cc2;
          float o;
          if (mode == 5) {
            float d2 = sqb[R] + sqb[Cc2] - 2.f * v;
            o = (R == Cc2) ? 0.f : expf(-d2);
          } else if (mode == 4) {
            o = fmaxf(v + bias[R], 0.f);
          } else {
            o = alpha * v;
            if (Dh) o += beta * pget(Dh, Dl, (long long)R * ldd + Cc2);
          }
          if (mode == 2) atomicAdd(&C[idx], o);
          else pput(Ch, Cl, idx, o);
        }
      }
    }
  }
}

// ---------------- skinny GEMM for Nc<=16 (L1 recurrence) ----------------
// atomicAdd(C, alpha * A(MxK) @ BT(NcxK)^T).  M%128==0, K%32==0.  B direct-to-reg.
static __global__ __launch_bounds__(256) void gemm_skinny(
    const short* __restrict__ Ah, const short* __restrict__ Al, int lda, long long sA,
    const short* __restrict__ Bh, const short* __restrict__ Bl, long long ldb, long long sB,
    float* C, int ldc, long long sC,
    int M, int K, int Nc, float alpha, int ksplit) {
  int bz = blockIdx.z;
  int zb = bz / ksplit, zk = bz - zb * ksplit;
  Ah += (long long)zb * sA; Al += (long long)zb * sA;
  Bh += (long long)zb * sB; Bl += (long long)zb * sB;
  C += (long long)zb * sC;
  int kslice = (((K / ksplit) + 31) >> 5) << 5;
  int k_begin = zk * kslice, k_end = min(K, k_begin + kslice);
  int nt = (k_end - k_begin) >> 5;

  __shared__ __align__(16) short sm[2][4][128][8];  // 16 KB

  int t = threadIdx.x, w = t >> 6, lane = t & 63, g = lane >> 4, c = lane & 15;
  int row0 = blockIdx.y * 128;

  f32x4 acc[2];
#pragma unroll
  for (int f = 0; f < 2; ++f) { acc[f][0] = 0.f; acc[f][1] = 0.f; acc[f][2] = 0.f; acc[f][3] = 0.f; }

  if (nt > 0) {
    for (int tt = 0; tt < nt; ++tt) {
      int k0 = k_begin + tt * 32;
#pragma unroll
      for (int q = 0; q < 4; ++q) {
        int idx = q * 256 + t;
        int plane = idx >> 9, rem = idx & 511, kb = rem >> 7, row = rem & 127;
        const short* src = (plane ? Al : Ah) + (long long)(row0 + row) * lda + k0 + kb * 8;
        GLOAD16(src, &sm[0][0][0][0] + idx * 8);
      }
      __syncthreads();
      s16x8 bh = *reinterpret_cast<const s16x8*>(Bh + (long long)c * ldb + k0 + g * 8);
      s16x8 bl = *reinterpret_cast<const s16x8*>(Bl + (long long)c * ldb + k0 + g * 8);
      s16x8 aH0 = *reinterpret_cast<const s16x8*>(&sm[0][g][w * 32 + c][0]);
      s16x8 aH1 = *reinterpret_cast<const s16x8*>(&sm[0][g][w * 32 + 16 + c][0]);
      s16x8 aL0 = *reinterpret_cast<const s16x8*>(&sm[1][g][w * 32 + c][0]);
      s16x8 aL1 = *reinterpret_cast<const s16x8*>(&sm[1][g][w * 32 + 16 + c][0]);
      acc[0] = __builtin_amdgcn_mfma_f32_16x16x32_bf16(aH0, bh, acc[0], 0, 0, 0);
      acc[0] = __builtin_amdgcn_mfma_f32_16x16x32_bf16(aH0, bl, acc[0], 0, 0, 0);
      acc[0] = __builtin_amdgcn_mfma_f32_16x16x32_bf16(aL0, bh, acc[0], 0, 0, 0);
      acc[1] = __builtin_amdgcn_mfma_f32_16x16x32_bf16(aH1, bh, acc[1], 0, 0, 0);
      acc[1] = __builtin_amdgcn_mfma_f32_16x16x32_bf16(aH1, bl, acc[1], 0, 0, 0);
      acc[1] = __builtin_amdgcn_mfma_f32_16x16x32_bf16(aL1, bh, acc[1], 0, 0, 0);
      __syncthreads();
    }
  }
#pragma unroll
  for (int f = 0; f < 2; ++f)
#pragma unroll
    for (int r = 0; r < 4; ++r) {
      int R = row0 + w * 32 + f * 16 + g * 4 + r;
      if (c < Nc && R < M) atomicAdd(&C[(long long)R * ldc + c], alpha * acc[f][r]);
    }
}

// ---------------- reductions / pool / FC ----------------

static __global__ void sumsq_kernel(const float* __restrict__ src, long long n, float* out) {
  float s = 0.f;
  long long i = (long long)blockIdx.x * blockDim.x + threadIdx.x;
  long long st = (long long)gridDim.x * blockDim.x;
  for (; i < n; i += st) { float v = src[i]; s += v * v; }
  __shared__ float red[256];
  red[threadIdx.x] = s;
  __syncthreads();
  for (int stp = 128; stp > 0; stp >>= 1) {
    if (threadIdx.x < stp) red[threadIdx.x] += red[threadIdx.x + stp];
    __syncthreads();
  }
  if (threadIdx.x == 0) atomicAdd(out, red[0]);
}

// g[b*F+f] = max_n (H planes)[f][b*N+n]
static __global__ void maxpool_p(const short* __restrict__ Hh, const short* __restrict__ Hl,
                                 float* __restrict__ g, int N, long long GN, int F, int Gb) {
  int wid = (int)(((long long)blockIdx.x * blockDim.x + threadIdx.x) >> 6);
  int lane = threadIdx.x & 63;
  if (wid >= Gb * F) return;
  int b = wid / F, f = wid - b * F;
  long long base = (long long)f * GN + (long long)b * N;
  float m = -INFINITY;
  for (int n = lane; n < N; n += 64) m = fmaxf(m, pget(Hh, Hl, base + n));
  for (int off = 32; off; off >>= 1) m = fmaxf(m, __shfl_down(m, off));
  if (lane == 0) g[(long long)b * F + f] = m;
}

static __global__ void fc_kernel(const float* __restrict__ in, const float* __restrict__ W,
                                 const float* __restrict__ bias, float* out,
                                 int Bc, int K, int J, int do_relu) {
  int gtid = blockIdx.x * blockDim.x + threadIdx.x;
  int wid = gtid >> 6;
  int lane = gtid & 63;
  if (wid >= Bc * J) return;
  int b = wid / J, j = wid - b * J;
  const float* ib = in + (long long)b * K;
  const float* wj = W + (long long)j * K;
  float s = 0.f;
  for (int k = lane; k < K; k += 64) s += ib[k] * wj[k];
  for (int off = 32; off > 0; off >>= 1) s += __shfl_down(s, off);
  if (lane == 0) {
    s += bias[j];
    out[wid] = do_relu ? fmaxf(s, 0.f) : s;
  }
}

static __global__ void finalize_kernel(const float* scal, float* out_regs) {
  if (threadIdx.x == 0 && blockIdx.x == 0) {
    float r1 = sqrtf(scal[0]), r2 = sqrtf(scal[1]), r3 = sqrtf(scal[2]);
    float nw = sqrtf(scal[3]), nb = sqrtf(scal[4]);
    out_regs[0] = r1; out_regs[1] = r2; out_regs[2] = r3;
    out_regs[3] = nw; out_regs[4] = nb;
    out_regs[5] = nw; out_regs[6] = nb;
    out_regs[7] = nw; out_regs[8] = nb;
  }
}

// ---------------- host orchestration ----------------

struct Ptrs {
  short *Lh, *Ll, *Tch, *Tcl, *TTh, *TTl, *Xgh, *Xgl;
  short *HTAh, *HTAl, *HTBh, *HTBl, *LHh, *LHl;
  short *W1h, *W1l, *W2h, *W2l, *W3h, *W3l;
  float *Trec, *Mm1, *Mm2, *Mm3, *sq, *dinv, *gb, *o1, *o2, *scal;
};

extern "C" void kernel_launch(void* const* d_in, const int* in_sizes, int n_in,
                              void* d_out, int out_size, void* d_ws, size_t ws_size,
                              hipStream_t stream) {
  const float* x   = (const float*)d_in[0];
  const float* w1  = (const float*)d_in[4];
  const float* b1  = (const float*)d_in[5];
  const float* w2  = (const float*)d_in[6];
  const float* b2  = (const float*)d_in[7];
  const float* w3  = (const float*)d_in[8];
  const float* b3  = (const float*)d_in[9];
  const float* fw1 = (const float*)d_in[10];
  const float* fb1 = (const float*)d_in[11];
  const float* fw2 = (const float*)d_in[12];
  const float* fb2 = (const float*)d_in[13];
  const float* fw3 = (const float*)d_in[14];
  const float* fb3 = (const float*)d_in[15];
  float* out = (float*)d_out;

  float* ws = (float*)d_ws;
  const long long NN = (long long)N_ * N_;

  Ptrs p;
  auto layout = [&](int G) -> unsigned long long {
    long long off = 0;  // in floats
    auto aF = [&](long long n) { float* q = ws + off; off += (n + 7) & ~7LL; return q; };
    auto aS = [&](long long n) { short* q = (short*)(ws + off); off += (((n + 1) >> 1) + 7) & ~7LL; return q; };
    long long GN = (long long)G * N_;
    p.Lh = aS(G * NN); p.Ll = aS(G * NN);
    p.Tch = aS(GN * 1536); p.Tcl = aS(GN * 1536);
    p.TTh = aS(GN * 512); p.TTl = aS(GN * 512);
    p.Xgh = aS(GN * 32); p.Xgl = aS(GN * 32);
    p.HTAh = aS(GN * 1024); p.HTAl = aS(GN * 1024);
    p.HTBh = aS(GN * 1024); p.HTBl = aS(GN * 1024);
    p.LHh = aS(GN * 1024); p.LHl = aS(GN * 1024);
    p.W1h = aS(128 * 64); p.W1l = aS(128 * 64);
    p.W2h = aS(512 * 640); p.W2l = aS(512 * 640);
    p.W3h = aS(1024 * 1536); p.W3l = aS(1024 * 1536);
    p.Trec = aF(GN * 512);
    p.Mm1 = aF(128 * 128); p.Mm2 = aF(512 * 512); p.Mm3 = aF(1024 * 1024);
    p.sq = aF(GN); p.dinv = aF(GN);
    p.gb = aF(B_ * 1024); p.o1 = aF(B_ * 512); p.o2 = aF(B_ * 128);
    p.scal = aF(16);
    return (unsigned long long)off * 4ULL;
  };
  int G = 16;
  while (G > 1 && layout(G) > ws_size) G >>= 1;
  if (layout(G) > ws_size) return;
  layout(G);

  const long long GN = (long long)G * N_;
  auto blk1d = [](long long n) { return (int)(((n + 255) / 256 < 4096) ? (n + 255) / 256 : 4096); };

  // split factors (target ~512+ blocks per heavy launch)
  int skSK = 64 / G; if (skSK < 1) skSK = 1;       // L1 recurrence (skinny)
  int rsk128 = 64 / G; if (rsk128 < 1) rsk128 = 1; // L2 recurrence
  int rsk512 = 16 / G; if (rsk512 < 1) rsk512 = 1; // L3 recurrence
  int mm1SK = (int)(GN / 64); if (mm1SK > 512) mm1SK = 512; if (mm1SK < 1) mm1SK = 1;
  int mm2SK = 32, mm3SK = 8;

  // ---- W plane conversions (Fout x Kpad, tap k at col k*Fin) ----
  cvt_tr_kernel<<<dim3(4, 1, 6), dim3(32, 8), 0, stream>>>(
      w1, 128, 6LL * 128, p.W1h, p.W1l, 64, 6, 6, 128);
  pad0_kernel<<<blk1d(128LL * 28), 256, 0, stream>>>(p.W1h, p.W1l, 64, 128, 36, 64);
  cvt_tr_kernel<<<dim3(16, 4, 5), dim3(32, 8), 0, stream>>>(
      w2, 512, 128LL * 512, p.W2h, p.W2l, 640, 128, 128, 512);
  cvt_tr_kernel<<<dim3(32, 16, 3), dim3(32, 8), 0, stream>>>(
      w3, 1024, 512LL * 1024, p.W3h, p.W3l, 1536, 512, 512, 1024);
  // persistent pads (rewritten never, only cols<valid written per chunk)
  pad0_kernel<<<blk1d(GN * 26), 256, 0, stream>>>(p.Xgh, p.Xgl, 32, GN, 6, 32);
  pad0_kernel<<<blk1d(GN * 28), 256, 0, stream>>>(p.Tch, p.Tcl, 64, GN, 36, 64);

  zerof_kernel<<<1, 256, 0, stream>>>(p.scal, 16);
  zerof_kernel<<<64, 256, 0, stream>>>(p.Mm1, 128LL * 128);
  zerof_kernel<<<256, 256, 0, stream>>>(p.Mm2, 512LL * 512);
  zerof_kernel<<<1024, 256, 0, stream>>>(p.Mm3, 1024LL * 1024);

  auto do_layer = [&](const float* Xrm, const short* pHTh, const short* pHTl,
                      int Fin, int taps, int Fout, const float* bias,
                      const short* Wh, const short* Wl, int Kpad,
                      short* oHTh, short* oHTl, int recSK, int mmSK, float* Mm) {
    // ---- input prep: sq, T0 row-major planes (Tch col 0), T0^T planes ----
    if (Xrm) {
      rowsq_small<<<blk1d(GN), 256, 0, stream>>>(Xrm, p.sq, 6, GN);
      cvt_rm_kernel<<<blk1d(GN * 6), 256, 0, stream>>>(Xrm, 6, p.Tch, p.Tcl, 64, GN, 6);
      cvt_rm_kernel<<<blk1d(GN * 6), 256, 0, stream>>>(Xrm, 6, p.Xgh, p.Xgl, 32, GN, 6);
      cvt_tr_kernel<<<dim3(1, 64, G), dim3(32, 8), 0, stream>>>(
          Xrm, 6, (long long)N_ * 6, p.TTh, p.TTl, GN, N_, N_, 6);
    } else {
      colsq_p<<<blk1d(GN), 256, 0, stream>>>(pHTh, pHTl, p.sq, Fin, GN);
      tr_pp_kernel<<<dim3((int)(GN / 32), Fin / 32), dim3(32, 8), 0, stream>>>(
          pHTh, pHTl, GN, p.Tch, p.Tcl, Kpad, Fin, GN);
    }
    // ---- graph -> L planes (mode 5) ----
    const short* Gh = Xrm ? p.Xgh : p.Tch;
    const short* Gl = Xrm ? p.Xgl : p.Tcl;
    int glda = Xrm ? 32 : Kpad;
    int GK = Xrm ? 32 : Fin;
    gemm_mf<<<dim3(16, 16, G), 256, 0, stream>>>(
        Gh, Gl, glda, (long long)N_ * glda, Gh, Gl, glda, (long long)N_ * glda,
        nullptr, nullptr, 0, 0, nullptr, p.Lh, p.Ll, N_, NN,
        N_, GK, N_, 1.f, 0.f, 5, p.sq, N_, 1, nullptr);
    rowsum_dinv_p<<<(int)GN, 256, 0, stream>>>(p.Lh, p.Ll, p.dinv, N_);
    scaleL_p<<<4096, 256, 0, stream>>>(p.Lh, p.Ll, p.dinv, G * NN);
    // ---- chebyshev recurrence ----
    for (int k = 1; k < taps; ++k) {
      if (k == 1) {
        zerof_kernel<<<blk1d(GN * Fin), 256, 0, stream>>>(p.Trec, GN * Fin);
      } else if (k == 2 && Xrm) {
        initC_kernel<<<blk1d(GN * Fin), 256, 0, stream>>>(p.Trec, Fin, Xrm, Fin, GN, Fin, -1.f);
      } else {
        initCp_kernel<<<blk1d(GN * Fin), 256, 0, stream>>>(
            p.Trec, Fin, p.Tch + (long long)(k - 2) * Fin, p.Tcl + (long long)(k - 2) * Fin,
            Kpad, GN, Fin, -1.f);
      }
      const short* Bh_ = (k == 1 && !Xrm) ? pHTh : p.TTh;
      const short* Bl_ = (k == 1 && !Xrm) ? pHTl : p.TTl;
      float alpha = (k == 1) ? 1.f : 2.f;
      if (Fin == 6) {
        gemm_skinny<<<dim3(1, 16, G * recSK), 256, 0, stream>>>(
            p.Lh, p.Ll, N_, NN, Bh_, Bl_, GN, N_,
            p.Trec, Fin, (long long)N_ * Fin, N_, N_, Fin, alpha, recSK);
      } else {
        gemm_mf<<<dim3(Fin / 128, 16, G * recSK), 256, 0, stream>>>(
            p.Lh, p.Ll, N_, NN, Bh_, Bl_, (int)GN, N_,
            nullptr, nullptr, 0, 0, p.Trec, nullptr, nullptr, Fin, (long long)N_ * Fin,
            N_, N_, Fin, alpha, 0.f, 2, nullptr, 0, recSK, nullptr);
      }
      cvt_dual_kernel<<<dim3((Fin + 31) / 32, (int)(GN / 32)), dim3(32, 8), 0, stream>>>(
          p.Trec, Fin, p.Tch + (long long)k * Fin, p.Tcl + (long long)k * Fin, Kpad,
          p.TTh, p.TTl, GN, (int)GN, Fin);
    }
    // ---- projection (mode 4): H^T planes = relu(Wcat^T @ Tcat^T + bias) ----
    gemm_mf<<<dim3((int)(GN / 128), Fout / 128, 1), 256, 0, stream>>>(
        Wh, Wl, Kpad, 0, p.Tch, p.Tcl, Kpad, 0,
        nullptr, nullptr, 0, 0, nullptr, oHTh, oHTl, (int)GN, 0,
        Fout, Kpad, (int)GN, 1.f, 0.f, 4, nullptr, 0, 1, bias);
    // ---- LHT = H^T L + H^T (mode 3, plane D) ----
    gemm_mf<<<dim3(16, Fout / 128, G), 256, 0, stream>>>(
        oHTh, oHTl, (int)GN, N_, p.Lh, p.Ll, N_, NN,
        oHTh, oHTl, (int)GN, N_, nullptr, p.LHh, p.LHl, (int)GN, N_,
        Fout, N_, N_, 1.f, 1.f, 3, nullptr, 0, 1, nullptr);
    // ---- Mm += H^T (L+I) H (mode 2, split-K) ----
    gemm_mf<<<dim3(Fout / 128, Fout / 128, mmSK), 256, 0, stream>>>(
        oHTh, oHTl, (int)GN, 0, p.LHh, p.LHl, (int)GN, 0,
        nullptr, nullptr, 0, 0, Mm, nullptr, nullptr, Fout, 0,
        Fout, (int)GN, Fout, 1.f, 0.f, 2, nullptr, 0, mmSK, nullptr);
  };

  for (int c = 0; c < B_ / G; ++c) {
    const float* Xc = x + (long long)c * GN * 6;
    do_layer(Xc, nullptr, nullptr, 6, 6, 128, b1, p.W1h, p.W1l, 64, p.HTAh, p.HTAl, skSK, mm1SK, p.Mm1);
    do_layer(nullptr, p.HTAh, p.HTAl, 128, 5, 512, b2, p.W2h, p.W2l, 640, p.HTBh, p.HTBl, rsk128, mm2SK, p.Mm2);
    do_layer(nullptr, p.HTBh, p.HTBl, 512, 3, 1024, b3, p.W3h, p.W3l, 1536, p.HTAh, p.HTAl, rsk512, mm3SK, p.Mm3);
    maxpool_p<<<(G * 1024 * 64 + 255) / 256, 256, 0, stream>>>(
        p.HTAh, p.HTAl, p.gb + (long long)c * G * 1024, N_, GN, 1024, G);
  }

  sumsq_kernel<<<64, 256, 0, stream>>>(p.Mm1, 128LL * 128, p.scal + 0);
  sumsq_kernel<<<256, 256, 0, stream>>>(p.Mm2, 512LL * 512, p.scal + 1);
  sumsq_kernel<<<256, 256, 0, stream>>>(p.Mm3, 1024LL * 1024, p.scal + 2);

  fc_kernel<<<(B_ * 512 * 64 + 255) / 256, 256, 0, stream>>>(p.gb, fw1, fb1, p.o1, B_, 1024, 512, 1);
  fc_kernel<<<(B_ * 128 * 64 + 255) / 256, 256, 0, stream>>>(p.o1, fw2, fb2, p.o2, B_, 512, 128, 1);
  fc_kernel<<<(B_ * 10 * 64 + 255) / 256, 256, 0, stream>>>(p.o2, fw3, fb3, out, B_, 128, 10, 0);

  sumsq_kernel<<<256, 256, 0, stream>>>(fw1, 512LL * 1024, p.scal + 3);
  sumsq_kernel<<<1, 256, 0, stream>>>(fb1, 512LL, p.scal + 4);
  finalize_kernel<<<1, 64, 0, stream>>>(p.scal, out + 160);
}